// Round 9
// baseline (832.248 us; speedup 1.0000x reference)
//
#include <hip/hip_runtime.h>
#include <hip/hip_bf16.h>
#include <hip/hip_fp16.h>
#include <stdint.h>

#define N_NODES 100000
#define N_EDGES 1600000
#define IN_DIM 256
#define HID 128
#define N_LAYERS 4
#define OUT_DIM 7
#define LN_EPS 1e-5f

// counting-sort CSR build
#define BSHIFT 6
#define BROWS 64
#define NBK 1563                  // ceil(100000/64) buckets of 64 rows
#define CHUNK 16384               // edges per sort block
#define NCH ((N_EDGES + CHUNK - 1) / CHUNK)   // 98 (must be <= 128 for k_hscan)

typedef __attribute__((ext_vector_type(8))) short bf16x8;
typedef __attribute__((ext_vector_type(4))) float f32x4;

__device__ inline float bf2f1(uint16_t u) {
    union { uint32_t i; float f; } a; a.i = ((uint32_t)u) << 16; return a.f;
}
__device__ inline uint16_t f2bf(float f) {
    union { float f; uint32_t i; } a; a.f = f;
    uint32_t lsb = (a.i >> 16) & 1u;
    a.i += 0x7fffu + lsb;          // round-to-nearest-even
    return (uint16_t)(a.i >> 16);
}
__device__ inline uint32_t packq(float a, float b, float qinv) {
    int qa = __float2int_rn(a * qinv);
    int qb = __float2int_rn(b * qinv);
    return ((uint32_t)(uint16_t)(short)qa) | (((uint32_t)(uint16_t)(short)qb) << 16);
}

// fragment-order W pack: lane-linear so LDS B-frag read is one contiguous 16B.
// element (k, c) of W[KD][128] -> ((ksg*8 + ct)*64 + lane)*8 + e
__device__ __host__ inline int wpack_idx(int k, int c) {
    int ksg = k >> 5, lg = (k >> 3) & 3, e = k & 7;
    int ct = c >> 4, li = c & 15;
    return ((ksg * 8 + ct) * 64 + (lg * 16 + li)) * 8 + e;
}

// ---------------- dtype detection ----------------
__global__ void k_detect(const uint32_t* __restrict__ W, int* __restrict__ flag) {
    if (threadIdx.x == 0 && blockIdx.x == 0) {
        int cnt = 0;
        for (int i = 0; i < 64; i++) {
            uint32_t lo = W[i] & 0xffffu;
            uint32_t ex = (lo >> 7) & 0xff;
            if (ex >= 0x60 && ex < 0x7c) cnt++;
        }
        *flag = (cnt < 32) ? 1 : 0;   // 1 = fp32 inputs, 0 = bf16 inputs
    }
}
__global__ void k_setflag(int* __restrict__ flag, int v) {
    if (threadIdx.x == 0) *flag = v;
}

// ---------------- weight canonicalization (all weights -> fp32 staged) ----------------
__global__ __launch_bounds__(256) void k_cvt(const void* a0, const void* a1, const void* a2,
                                             const void* a3, const void* a4, const void* a5,
                                             const void* a6, const void* a7, const void* a8,
                                             float* __restrict__ dst, const int* __restrict__ flag) {
    int t = blockIdx.x * 256 + threadIdx.x;
    if (t >= 99720) return;
    const void* src; int i; int off;
    if      (t < 32768) { src = a0; i = t;         off = 0;     }   // W_proj 256x128
    else if (t < 32896) { src = a1; i = t - 32768; off = 32768; }   // b_proj 128
    else if (t < 33024) { src = a2; i = t - 32896; off = 32896; }   // gamma 128
    else if (t < 33152) { src = a3; i = t - 33024; off = 33024; }   // beta 128
    else if (t < 33280) { src = a4; i = t - 33152; off = 33152; }   // q_w 128
    else if (t < 33281) { src = a5; i = t - 33280; off = 33280; }   // q_b 1
    else if (t < 98817) { src = a6; i = t - 33281; off = 33296; }   // conv_w 4x128x128
    else if (t < 99713) { src = a7; i = t - 98817; off = 98832; }   // cls_w 128x7
    else                { src = a8; i = t - 99713; off = 99728; }   // cls_b 7
    float v;
    if (*flag) v = ((const float*)src)[i];
    else       v = bf2f1(((const uint16_t*)src)[i]);
    dst[off + i] = v;
}

// ---------------- split-bf16 weight prep, fragment/lane-ordered ----------------
__global__ __launch_bounds__(256) void k_wsplit(const float* __restrict__ stg,
                                                uint16_t* __restrict__ wpkhi, uint16_t* __restrict__ wpklo,
                                                uint16_t* __restrict__ cwkhi, uint16_t* __restrict__ cwklo) {
    int t = blockIdx.x * 256 + threadIdx.x;
    if (t >= 32768 + 65536) return;
    float v; size_t dst; uint16_t *ha, *la;
    if (t < 32768) {
        int k = t >> 7, c = t & 127;
        v = stg[t];
        dst = (size_t)wpack_idx(k, c); ha = wpkhi; la = wpklo;
    } else {
        int u = t - 32768;
        int L = u >> 14, rem = u & 16383;
        int k = rem >> 7, c = rem & 127;
        v = stg[33296 + u];
        dst = (size_t)L * 16384 + wpack_idx(k, c); ha = cwkhi; la = cwklo;
    }
    uint16_t hb = f2bf(v);
    uint16_t lb = f2bf(v - bf2f1(hb));
    ha[dst] = hb; la[dst] = lb;
}

// ---------------- graph prep: atomic-free counting-sort CSR build ----------------

__global__ __launch_bounds__(256) void k_hist(const int* __restrict__ row, int* __restrict__ hist) {
    __shared__ int lh[NBK];
    int b = blockIdx.x, tid = threadIdx.x;
    for (int i = tid; i < NBK; i += 256) lh[i] = 0;
    __syncthreads();
    int e0 = b * CHUNK;
    int lim = N_EDGES - e0; if (lim > CHUNK) lim = CHUNK;
    for (int i = tid; i < lim; i += 256) atomicAdd(&lh[row[e0 + i] >> BSHIFT], 1);
    __syncthreads();
    for (int i = tid; i < NBK; i += 256) hist[(size_t)b * NBK + i] = lh[i];
}

__global__ __launch_bounds__(128) void k_hscan(int* __restrict__ hist, int* __restrict__ totB) {
    __shared__ int s[128];
    int bkt = blockIdx.x, t = threadIdx.x;
    int v = (t < NCH) ? hist[(size_t)t * NBK + bkt] : 0;
    s[t] = v;
    __syncthreads();
    for (int off = 1; off < 128; off <<= 1) {
        int add = (t >= off) ? s[t - off] : 0;
        __syncthreads();
        s[t] += add;
        __syncthreads();
    }
    if (t < NCH) hist[(size_t)t * NBK + bkt] = s[t] - v;   // exclusive within bucket
    if (t == 127) totB[bkt] = s[127];
}

__global__ __launch_bounds__(256) void k_bscan(const int* __restrict__ totB,
                                               int* __restrict__ boffB, int* __restrict__ rp) {
    __shared__ int ps[256];
    int t = threadIdx.x;
    const int STRIP = 7;                     // 256*7 = 1792 >= NBK
    int base = t * STRIP;
    int loc[STRIP]; int sum = 0;
#pragma unroll
    for (int j = 0; j < STRIP; j++) {
        int idx = base + j;
        int v = (idx < NBK) ? totB[idx] : 0;
        loc[j] = sum; sum += v;
    }
    ps[t] = sum;
    __syncthreads();
    int v = ps[t];
    for (int off = 1; off < 256; off <<= 1) {
        int add = (t >= off) ? ps[t - off] : 0;
        __syncthreads();
        ps[t] += add;
        __syncthreads();
    }
    int excl = ps[t] - v;
#pragma unroll
    for (int j = 0; j < STRIP; j++) {
        int idx = base + j;
        if (idx < NBK) boffB[idx] = excl + loc[j];
    }
    if (t == 0) { boffB[NBK] = N_EDGES; rp[N_NODES] = N_EDGES; }
}

__global__ __launch_bounds__(256) void k_sortscat(const int* __restrict__ row, const int* __restrict__ col,
                                                  const int* __restrict__ hist, const int* __restrict__ boffB,
                                                  uint32_t* __restrict__ ebp) {
    __shared__ int dbase[NBK];
    __shared__ int lcnt[NBK];
    int b = blockIdx.x, tid = threadIdx.x;
    for (int i = tid; i < NBK; i += 256) {
        dbase[i] = boffB[i] + hist[(size_t)b * NBK + i];
        lcnt[i] = 0;
    }
    __syncthreads();
    int e0 = b * CHUNK;
    int lim = N_EDGES - e0; if (lim > CHUNK) lim = CHUNK;
    for (int i = tid; i < lim; i += 256) {
        int r = row[e0 + i], c = col[e0 + i];
        int bk = r >> BSHIFT;
        int rank = atomicAdd(&lcnt[bk], 1);
        ebp[dbase[bk] + rank] = ((uint32_t)(r & (BROWS - 1)) << 17) | (uint32_t)c;
    }
}

__global__ __launch_bounds__(256) void k_bfin(const uint32_t* __restrict__ ebp, const int* __restrict__ boffB,
                                              int* __restrict__ rp, float* __restrict__ dis,
                                              int* __restrict__ edc) {
    __shared__ int ldeg[BROWS];
    __shared__ int lcur[BROWS];
    int b = blockIdx.x, tid = threadIdx.x;
    int base = boffB[b];
    int n = boffB[b + 1] - base;
    if (tid < BROWS) ldeg[tid] = 0;
    __syncthreads();
    for (int i = tid; i < n; i += 256) atomicAdd(&ldeg[ebp[base + i] >> 17], 1);
    __syncthreads();
    if (tid == 0) {
        int run = 0;
        for (int r = 0; r < BROWS; r++) { int d = ldeg[r]; lcur[r] = run; run += d; }
    }
    __syncthreads();
    int row0 = b << BSHIFT;
    if (tid < BROWS && row0 + tid < N_NODES) {
        int d = ldeg[tid];
        rp[row0 + tid]  = base + lcur[tid];
        dis[row0 + tid] = rsqrtf((float)(d > 0 ? d : 1));
    }
    __syncthreads();   // rp/dis read lcur before scatter mutates it
    for (int i = tid; i < n; i += 256) {
        uint32_t pk = ebp[base + i];
        int r = pk >> 17;
        int pos = atomicAdd(&lcur[r], 1);
        edc[base + pos] = (int)(pk & 0x1FFFFu);
    }
}

// ---------------- fused SpMM + blend (int16 mirror + per-row scale, proven numerics) --

__global__ __launch_bounds__(256) void k_spmm(const uint32_t* __restrict__ Hq,
                                              const float* __restrict__ ScD,
                                              const float* __restrict__ H0,
                                              const int* __restrict__ rp,
                                              const int* __restrict__ edc,
                                              const float* __restrict__ S,
                                              const float* __restrict__ dis,
                                              uint16_t* __restrict__ SupHi,
                                              uint16_t* __restrict__ SupLo) {
    int wid  = (blockIdx.x * 256 + threadIdx.x) >> 6;
    int lane = threadIdx.x & 63;
    if (wid >= N_NODES) return;

    float s  = S[wid];
    float dr = dis[wid];
    float h0x = H0[(size_t)wid * 128 + lane];
    float h0y = H0[(size_t)wid * 128 + 64 + lane];

    int p0 = rp[wid], p1 = rp[wid + 1];
    float ax = 0.f, ay = 0.f;
    int p = p0;
    for (; p + 16 <= p1; p += 16) {
        int c[16]; uint32_t u[16]; float w[16];
#pragma unroll
        for (int j = 0; j < 16; j++) c[j] = edc[p + j];
#pragma unroll
        for (int j = 0; j < 16; j++) u[j] = Hq[(size_t)c[j] * 64 + lane];
#pragma unroll
        for (int j = 0; j < 16; j++) w[j] = ScD[c[j]];
#pragma unroll
        for (int j = 0; j < 16; j++) {
            ax += w[j] * (float)((int)(u[j] << 16) >> 16);
            ay += w[j] * (float)((int)u[j] >> 16);
        }
    }
    for (; p + 4 <= p1; p += 4) {
        int c[4]; uint32_t u[4]; float w[4];
#pragma unroll
        for (int j = 0; j < 4; j++) c[j] = edc[p + j];
#pragma unroll
        for (int j = 0; j < 4; j++) u[j] = Hq[(size_t)c[j] * 64 + lane];
#pragma unroll
        for (int j = 0; j < 4; j++) w[j] = ScD[c[j]];
#pragma unroll
        for (int j = 0; j < 4; j++) {
            ax += w[j] * (float)((int)(u[j] << 16) >> 16);
            ay += w[j] * (float)((int)u[j] >> 16);
        }
    }
    for (; p < p1; p++) {
        int c = edc[p];
        uint32_t u = Hq[(size_t)c * 64 + lane];
        float w = ScD[c];
        ax += w * (float)((int)(u << 16) >> 16);
        ay += w * (float)((int)u >> 16);
    }
    float f = (1.f - s) * dr;
    float ox = f * ax + s * h0x;
    float oy = f * ay + s * h0y;
    uint16_t hx = f2bf(ox), hy = f2bf(oy);
    uint16_t lx = f2bf(ox - bf2f1(hx)), ly = f2bf(oy - bf2f1(hy));
    SupHi[(size_t)wid * 128 + lane]      = hx;
    SupHi[(size_t)wid * 128 + 64 + lane] = hy;
    SupLo[(size_t)wid * 128 + lane]      = lx;
    SupLo[(size_t)wid * 128 + 64 + lane] = ly;
}

// ---------------- MFMA GEMM: W 64-K chunk in LDS (32KB, 3 blk/CU), A in regs ----------
// Block = 128 rows, 4 waves; wave wv owns rows wb=wv*32 + {li, li+16} (two acc sets).
// Per 64-K chunk: stage W hi(+lo) 16(32)KB -> barrier -> barrier-free MFMA loop.
// C layout: col=lane&15, row=(lane>>4)*4+reg (per 16-row set).
// Split products: C = Ah*Wh [+ Al*Wh if A fp32] [+ Ah*Wl if W fp32].
// WQ: epilogue writes Hq int16 pairs + per-row scale Sc (dis-folded) + gate S.
// WC: classifier fused -> writes d_out logits directly (no final h materialized).

template <int KD, int MODE, int WH, int WQ, int WF, int WC>
__global__ __launch_bounds__(256, 3) void k_gemm(
    const void* __restrict__ Ax,
    const uint16_t* __restrict__ Ahi, const uint16_t* __restrict__ Alo,
    const uint16_t* __restrict__ Wh, const uint16_t* __restrict__ Wl,
    const float* __restrict__ bias, const float* __restrict__ gamma,
    const float* __restrict__ beta, const float* __restrict__ qw,
    const float* __restrict__ qb, float theta, const int* __restrict__ flag,
    const float* __restrict__ dis,
    float* __restrict__ Hout, uint32_t* __restrict__ Hq,
    float* __restrict__ Sc, float* __restrict__ S,
    const float* __restrict__ clw, const float* __restrict__ clb,
    void* __restrict__ Out)
{
    if (*flag != WF) return;             // guarded dual-launch fallback
    constexpr int F32A = (MODE == 0) ? WF : 1;   // A has a lo plane
    constexpr int NKB = KD / 64;

    __shared__ __align__(16) uint16_t sWh[8192];   // 16 KiB
    __shared__ __align__(16) uint16_t sWl[8192];   // 16 KiB -> 32 KiB total

    const int tid  = threadIdx.x;
    const int lane = tid & 63;
    const int wv   = tid >> 6;
    const int li   = lane & 15;
    const int lg   = lane >> 4;
    const size_t row0 = (size_t)blockIdx.x * 128;
    const int wb = wv * 32;
    size_t ar0 = row0 + wb + li;      if (ar0 >= N_NODES) ar0 = N_NODES - 1;
    size_t ar1 = row0 + wb + 16 + li; if (ar1 >= N_NODES) ar1 = N_NODES - 1;

    f32x4 acc0[8], acc1[8];
#pragma unroll
    for (int ct = 0; ct < 8; ct++) {
        acc0[ct] = (f32x4){0.f, 0.f, 0.f, 0.f};
        acc1[ct] = (f32x4){0.f, 0.f, 0.f, 0.f};
    }

    for (int kb = 0; kb < NKB; kb++) {
        if (kb) __syncthreads();
        const uint16_t* gh = Wh + kb * 8192;
#pragma unroll
        for (int it = 0; it < 4; it++) {
            int t = tid + it * 256;
            *(uint4*)(sWh + t * 8) = *(const uint4*)(gh + t * 8);
        }
        if constexpr (WF) {
            const uint16_t* gl = Wl + kb * 8192;
#pragma unroll
            for (int it = 0; it < 4; it++) {
                int t = tid + it * 256;
                *(uint4*)(sWl + t * 8) = *(const uint4*)(gl + t * 8);
            }
        }
        bf16x8 a0h[2], a1h[2], a0l[2], a1l[2];
#pragma unroll
        for (int s = 0; s < 2; s++) {
            const int koff = kb * 64 + s * 32 + lg * 8;
            if constexpr (MODE == 1) {
                a0h[s] = *(const bf16x8*)(Ahi + ar0 * KD + koff);
                a0l[s] = *(const bf16x8*)(Alo + ar0 * KD + koff);
                a1h[s] = *(const bf16x8*)(Ahi + ar1 * KD + koff);
                a1l[s] = *(const bf16x8*)(Alo + ar1 * KD + koff);
            } else if constexpr (WF) {
                const float* p0 = (const float*)Ax + ar0 * KD + koff;
                const float* p1 = (const float*)Ax + ar1 * KD + koff;
                float4 u0 = *(const float4*)p0, u1 = *(const float4*)(p0 + 4);
                float4 v0 = *(const float4*)p1, v1 = *(const float4*)(p1 + 4);
                float f0[8] = {u0.x, u0.y, u0.z, u0.w, u1.x, u1.y, u1.z, u1.w};
                float f1[8] = {v0.x, v0.y, v0.z, v0.w, v1.x, v1.y, v1.z, v1.w};
#pragma unroll
                for (int j = 0; j < 8; j++) {
                    uint16_t hb0 = f2bf(f0[j]);
                    a0h[s][j] = (short)hb0;
                    a0l[s][j] = (short)f2bf(f0[j] - bf2f1(hb0));
                    uint16_t hb1 = f2bf(f1[j]);
                    a1h[s][j] = (short)hb1;
                    a1l[s][j] = (short)f2bf(f1[j] - bf2f1(hb1));
                }
            } else {
                a0h[s] = *(const bf16x8*)((const uint16_t*)Ax + ar0 * KD + koff);
                a1h[s] = *(const bf16x8*)((const uint16_t*)Ax + ar1 * KD + koff);
            }
        }
        __syncthreads();
#pragma unroll
        for (int s = 0; s < 2; s++) {
#pragma unroll
            for (int ct = 0; ct < 8; ct++) {
                const int wo = ((s * 8 + ct) * 64 + lane) * 8;
                bf16x8 bh = *(const bf16x8*)(sWh + wo);
                acc0[ct] = __builtin_amdgcn_mfma_f32_16x16x32_bf16(a0h[s], bh, acc0[ct], 0, 0, 0);
                acc1[ct] = __builtin_amdgcn_mfma_f32_16x16x32_bf16(a1h[s], bh, acc1[ct], 0, 0, 0);
                if constexpr (F32A) {
                    acc0[ct] = __builtin_amdgcn_mfma_f32_16x16x32_bf16(a0l[s], bh, acc0[ct], 0, 0, 0);
                    acc1[ct] = __builtin_amdgcn_mfma_f32_16x16x32_bf16(a1l[s], bh, acc1[ct], 0, 0, 0);
                }
                if constexpr (WF) {
                    bf16x8 bl = *(const bf16x8*)(sWl + wo);
                    acc0[ct] = __builtin_amdgcn_mfma_f32_16x16x32_bf16(a0h[s], bl, acc0[ct], 0, 0, 0);
                    acc1[ct] = __builtin_amdgcn_mfma_f32_16x16x32_bf16(a1h[s], bl, acc1[ct], 0, 0, 0);
                }
            }
        }
    }

    // ---- epilogue: per (lane, reg, set) one row, cols {ct*16+li} ----
    float gm[8], bt_[8], qv[8], bi[8];
#pragma unroll
    for (int ct = 0; ct < 8; ct++) {
        int c = ct * 16 + li;
        gm[ct] = gamma[c]; bt_[ct] = beta[c]; qv[ct] = qw[c];
        bi[ct] = (MODE == 0) ? bias[c] : 0.f;
    }
    float wc[WC ? 56 : 1], cb[WC ? 7 : 1];
    if constexpr (WC) {
#pragma unroll
        for (int ct = 0; ct < 8; ct++)
#pragma unroll
            for (int j = 0; j < 7; j++) wc[ct * 7 + j] = clw[(ct * 16 + li) * 7 + j];
#pragma unroll
        for (int j = 0; j < 7; j++) cb[j] = clb[j];
    }
    const float qbv = qb[0];
    const float om  = 1.f - theta;

    auto epi = [&](f32x4 (&acc)[8], int ssoff) {
#pragma unroll
        for (int r = 0; r < 4; r++) {
            int rowl  = wb + ssoff + lg * 4 + r;
            size_t rg = row0 + rowl;
            size_t rc = (rg < N_NODES) ? rg : (N_NODES - 1);
            float v[8];
            if (MODE == 0) {
#pragma unroll
                for (int ct = 0; ct < 8; ct++) v[ct] = acc[ct][r] + bi[ct];
            } else {
#pragma unroll
                for (int ct = 0; ct < 8; ct++) {
                    int c = ct * 16 + li;
                    float sv = bf2f1(Ahi[rc * KD + c]) + bf2f1(Alo[rc * KD + c]);
                    float o  = theta * acc[ct][r] + om * sv;
                    v[ct] = o > 0.f ? o : 0.f;
                }
            }
            float sum = 0.f, sq = 0.f;
#pragma unroll
            for (int ct = 0; ct < 8; ct++) { sum += v[ct]; sq += v[ct] * v[ct]; }
            sum += __shfl_xor(sum, 1); sum += __shfl_xor(sum, 2);
            sum += __shfl_xor(sum, 4); sum += __shfl_xor(sum, 8);
            sq  += __shfl_xor(sq, 1);  sq  += __shfl_xor(sq, 2);
            sq  += __shfl_xor(sq, 4);  sq  += __shfl_xor(sq, 8);
            float mu  = sum * (1.f / 128.f);
            float var = fmaxf(sq * (1.f / 128.f) - mu * mu, 0.f);
            float rs  = rsqrtf(var + LN_EPS);
            float y[8];
#pragma unroll
            for (int ct = 0; ct < 8; ct++) y[ct] = gm[ct] * (v[ct] - mu) * rs + bt_[ct];

            if (WQ) {
                float zd = 0.f, am = 0.f;
#pragma unroll
                for (int ct = 0; ct < 8; ct++) { zd += y[ct] * qv[ct]; am = fmaxf(am, fabsf(y[ct])); }
                zd += __shfl_xor(zd, 1); zd += __shfl_xor(zd, 2);
                zd += __shfl_xor(zd, 4); zd += __shfl_xor(zd, 8);
                am = fmaxf(am, __shfl_xor(am, 1)); am = fmaxf(am, __shfl_xor(am, 2));
                am = fmaxf(am, __shfl_xor(am, 4)); am = fmaxf(am, __shfl_xor(am, 8));
                float amc  = fmaxf(am, 1e-20f);
                float qinv = 32767.f / amc;
                if (rg < N_NODES) {
                    uint32_t* mq = Hq + rg * 64;
#pragma unroll
                    for (int ct = 0; ct < 4; ct++)
                        mq[ct * 16 + li] = packq(y[ct], y[ct + 4], qinv);  // pair (c, c+64)
                    if (li == 0) {
                        Sc[rg] = amc * (1.f / 32767.f) * dis[rg];   // fold dis[col] into scale
                        S[rg]  = 1.f / (1.f + __expf(-(zd + qbv - 1.f)));
                    }
                }
            }
            if (WH && rg < N_NODES) {
                float* dst = Hout + rg * 128;
#pragma unroll
                for (int ct = 0; ct < 8; ct++) dst[ct * 16 + li] = y[ct];
            }
            if (WC && rg < N_NODES) {
#pragma unroll
                for (int j = 0; j < 7; j++) {
                    float z = 0.f;
#pragma unroll
                    for (int ct = 0; ct < 8; ct++) z += y[ct] * wc[ct * 7 + j];
                    z += __shfl_xor(z, 1); z += __shfl_xor(z, 2);
                    z += __shfl_xor(z, 4); z += __shfl_xor(z, 8);
                    if (li == j) {
                        size_t oi = rg * OUT_DIM + j;
                        if (WF) ((float*)Out)[oi] = z + cb[j];
                        else    ((uint16_t*)Out)[oi] = f2bf(z + cb[j]);
                    }
                }
            }
        }
    };
    epi(acc0, 0);
    epi(acc1, 16);
}

// ---------------- launch ----------------

extern "C" void kernel_launch(void* const* d_in, const int* in_sizes, int n_in,
                              void* d_out, int out_size, void* d_ws, size_t ws_size,
                              hipStream_t stream) {
    const void* x_raw = d_in[0];
    const int*  ei    = (const int*)d_in[1];
    const int* row = ei;
    const int* col = ei + N_EDGES;

    char* ws = (char*)d_ws;
    size_t off = 0;
    auto alloc = [&](size_t b) { void* p = ws + off; off = (off + b + 255) & ~(size_t)255; return p; };
    int*      flag = (int*)alloc(4);
    float*    stgf = (float*)alloc((size_t)99744 * 4);
    int*      rp   = (int*)alloc(((size_t)N_NODES + 1) * 4);
    float*    dis  = (float*)alloc((size_t)N_NODES * 4);
    int*      hist = (int*)alloc((size_t)NCH * NBK * 4);
    int*      totB = (int*)alloc((size_t)NBK * 4);
    int*      boffB= (int*)alloc(((size_t)NBK + 1) * 4);
    int*      edc  = (int*)alloc((size_t)N_EDGES * 4);             // CSR cols (4B)
    float*    h0   = (float*)alloc((size_t)N_NODES * HID * 4);     // h0 (spmm blend input)
    uint16_t* suphi= (uint16_t*)alloc((size_t)N_NODES * HID * 2);  // support hi plane
    uint16_t* suplo= (uint16_t*)alloc((size_t)N_NODES * HID * 2);  // support lo plane
    uint32_t* hq   = (uint32_t*)alloc((size_t)N_NODES * 64 * 4);   // int16 mirror
    float*    Scq  = (float*)alloc((size_t)N_NODES * 4);           // quant scale * dis
    float*    Sg   = (float*)alloc((size_t)N_NODES * 4);           // gate sigmoid
    uint16_t* wpkhi = (uint16_t*)alloc((size_t)32768 * 2);         // W_proj packed hi
    uint16_t* wpklo = (uint16_t*)alloc((size_t)32768 * 2);
    uint16_t* cwkhi = (uint16_t*)alloc((size_t)65536 * 2);         // conv_w packed hi (4 layers)
    uint16_t* cwklo = (uint16_t*)alloc((size_t)65536 * 2);
    uint32_t* ebp  = (uint32_t*)h0;   // bucket-sorted packed edges (6.4MB) alias h0

    const float* bp  = stgf + 32768;
    const float* gm  = stgf + 32896;
    const float* bt  = stgf + 33024;
    const float* qw  = stgf + 33152;
    const float* qb  = stgf + 33280;
    const float* clw = stgf + 98832;
    const float* clb = stgf + 99728;

    // host-side dtype detection from byte sizes; -1 = unknown -> guarded dual launch
    int hostflag = -1;
    if (in_sizes && n_in >= 3) {
        if      (in_sizes[2] == 32768 * 4) hostflag = 1;
        else if (in_sizes[2] == 32768 * 2) hostflag = 0;
        else if (in_sizes[0] == N_NODES * IN_DIM * 4) hostflag = 1;
        else if (in_sizes[0] == N_NODES * IN_DIM * 2) hostflag = 0;
    }
    if (hostflag >= 0) k_setflag<<<1, 64, 0, stream>>>(flag, hostflag);
    else               k_detect<<<1, 64, 0, stream>>>((const uint32_t*)d_in[2], flag);

    k_cvt<<<(99720 + 255) / 256, 256, 0, stream>>>(d_in[2], d_in[3], d_in[4], d_in[5], d_in[6],
                                                   d_in[7], d_in[8], d_in[9], d_in[10], stgf, flag);
    k_wsplit<<<(98304 + 255) / 256, 256, 0, stream>>>(stgf, wpkhi, wpklo, cwkhi, cwklo);

    k_hist<<<NCH, 256, 0, stream>>>(row, hist);
    k_hscan<<<NBK, 128, 0, stream>>>(hist, totB);
    k_bscan<<<1, 256, 0, stream>>>(totB, boffB, rp);
    k_sortscat<<<NCH, 256, 0, stream>>>(row, col, hist, boffB, ebp);
    k_bfin<<<NBK, 256, 0, stream>>>(ebp, boffB, rp, dis, edc);

    const int gg = (N_NODES + 127) / 128;   // 782
    if (hostflag != 0)
        k_gemm<IN_DIM, 0, 1, 1, 1, 0><<<gg, 256, 0, stream>>>(
            x_raw, nullptr, nullptr, wpkhi, wpklo, bp, gm, bt, qw, qb, 0.f, flag, dis,
            h0, hq, Scq, Sg, clw, clb, d_out);
    if (hostflag != 1)
        k_gemm<IN_DIM, 0, 1, 1, 0, 0><<<gg, 256, 0, stream>>>(
            x_raw, nullptr, nullptr, wpkhi, wpklo, bp, gm, bt, qw, qb, 0.f, flag, dis,
            h0, hq, Scq, Sg, clw, clb, d_out);

    for (int i = 0; i < N_LAYERS; i++) {
        k_spmm<<<(N_NODES + 3) / 4, 256, 0, stream>>>(hq, Scq, h0, rp, edc, Sg, dis, suphi, suplo);
        float theta = 0.5f / (float)(i + 1);
        const uint16_t* whi = cwkhi + (size_t)i * 16384;
        const uint16_t* wlo = cwklo + (size_t)i * 16384;
        if (i < N_LAYERS - 1) {
            if (hostflag != 0)
                k_gemm<HID, 1, 0, 1, 1, 0><<<gg, 256, 0, stream>>>(
                    nullptr, suphi, suplo, whi, wlo, nullptr, gm, bt, qw, qb, theta, flag, dis,
                    nullptr, hq, Scq, Sg, clw, clb, d_out);
            if (hostflag != 1)
                k_gemm<HID, 1, 0, 1, 0, 0><<<gg, 256, 0, stream>>>(
                    nullptr, suphi, suplo, whi, wlo, nullptr, gm, bt, qw, qb, theta, flag, dis,
                    nullptr, hq, Scq, Sg, clw, clb, d_out);
        } else {
            // last layer: classifier fused, no final h materialized
            if (hostflag != 0)
                k_gemm<HID, 1, 0, 0, 1, 1><<<gg, 256, 0, stream>>>(
                    nullptr, suphi, suplo, whi, wlo, nullptr, gm, bt, qw, qb, theta, flag, dis,
                    nullptr, hq, Scq, Sg, clw, clb, d_out);
            if (hostflag != 1)
                k_gemm<HID, 1, 0, 0, 0, 1><<<gg, 256, 0, stream>>>(
                    nullptr, suphi, suplo, whi, wlo, nullptr, gm, bt, qw, qb, theta, flag, dis,
                    nullptr, hq, Scq, Sg, clw, clb, d_out);
        }
    }
}

// Round 10
// 760.585 us; speedup vs baseline: 1.0942x; 1.0942x over previous
//
#include <hip/hip_runtime.h>
#include <hip/hip_bf16.h>
#include <hip/hip_fp16.h>
#include <stdint.h>

#define N_NODES 100000
#define N_EDGES 1600000
#define IN_DIM 256
#define HID 128
#define N_LAYERS 4
#define OUT_DIM 7
#define LN_EPS 1e-5f

// counting-sort CSR build
#define BSHIFT 6
#define BROWS 64
#define NBK 1563                  // ceil(100000/64) buckets of 64 rows
#define CHUNK 16384               // edges per sort block
#define NCH ((N_EDGES + CHUNK - 1) / CHUNK)   // 98 (must be <= 128 for k_hscan)

typedef __attribute__((ext_vector_type(8))) short bf16x8;
typedef __attribute__((ext_vector_type(4))) float f32x4;

__device__ inline float bf2f1(uint16_t u) {
    union { uint32_t i; float f; } a; a.i = ((uint32_t)u) << 16; return a.f;
}
__device__ inline uint16_t f2bf(float f) {
    union { float f; uint32_t i; } a; a.f = f;
    uint32_t lsb = (a.i >> 16) & 1u;
    a.i += 0x7fffu + lsb;          // round-to-nearest-even
    return (uint16_t)(a.i >> 16);
}
__device__ inline uint32_t packq(float a, float b, float qinv) {
    int qa = __float2int_rn(a * qinv);
    int qb = __float2int_rn(b * qinv);
    return ((uint32_t)(uint16_t)(short)qa) | (((uint32_t)(uint16_t)(short)qb) << 16);
}

// fragment-order W pack: lane-linear so LDS B-frag read is one contiguous 16B.
// element (k, c) of W[KD][128] -> ((ksg*8 + ct)*64 + lane)*8 + e
__device__ __host__ inline int wpack_idx(int k, int c) {
    int ksg = k >> 5, lg = (k >> 3) & 3, e = k & 7;
    int ct = c >> 4, li = c & 15;
    return ((ksg * 8 + ct) * 64 + (lg * 16 + li)) * 8 + e;
}

// ---------------- dtype detection ----------------
__global__ void k_detect(const uint32_t* __restrict__ W, int* __restrict__ flag) {
    if (threadIdx.x == 0 && blockIdx.x == 0) {
        int cnt = 0;
        for (int i = 0; i < 64; i++) {
            uint32_t lo = W[i] & 0xffffu;
            uint32_t ex = (lo >> 7) & 0xff;
            if (ex >= 0x60 && ex < 0x7c) cnt++;
        }
        *flag = (cnt < 32) ? 1 : 0;   // 1 = fp32 inputs, 0 = bf16 inputs
    }
}
__global__ void k_setflag(int* __restrict__ flag, int v) {
    if (threadIdx.x == 0) *flag = v;
}

// ---------------- weight canonicalization (all weights -> fp32 staged) ----------------
__global__ __launch_bounds__(256) void k_cvt(const void* a0, const void* a1, const void* a2,
                                             const void* a3, const void* a4, const void* a5,
                                             const void* a6, const void* a7, const void* a8,
                                             float* __restrict__ dst, const int* __restrict__ flag) {
    int t = blockIdx.x * 256 + threadIdx.x;
    if (t >= 99720) return;
    const void* src; int i; int off;
    if      (t < 32768) { src = a0; i = t;         off = 0;     }   // W_proj 256x128
    else if (t < 32896) { src = a1; i = t - 32768; off = 32768; }   // b_proj 128
    else if (t < 33024) { src = a2; i = t - 32896; off = 32896; }   // gamma 128
    else if (t < 33152) { src = a3; i = t - 33024; off = 33024; }   // beta 128
    else if (t < 33280) { src = a4; i = t - 33152; off = 33152; }   // q_w 128
    else if (t < 33281) { src = a5; i = t - 33280; off = 33280; }   // q_b 1
    else if (t < 98817) { src = a6; i = t - 33281; off = 33296; }   // conv_w 4x128x128
    else if (t < 99713) { src = a7; i = t - 98817; off = 98832; }   // cls_w 128x7
    else                { src = a8; i = t - 99713; off = 99728; }   // cls_b 7
    float v;
    if (*flag) v = ((const float*)src)[i];
    else       v = bf2f1(((const uint16_t*)src)[i]);
    dst[off + i] = v;
}

// ---------------- split-bf16 weight prep, fragment/lane-ordered ----------------
__global__ __launch_bounds__(256) void k_wsplit(const float* __restrict__ stg,
                                                uint16_t* __restrict__ wpkhi, uint16_t* __restrict__ wpklo,
                                                uint16_t* __restrict__ cwkhi, uint16_t* __restrict__ cwklo) {
    int t = blockIdx.x * 256 + threadIdx.x;
    if (t >= 32768 + 65536) return;
    float v; size_t dst; uint16_t *ha, *la;
    if (t < 32768) {
        int k = t >> 7, c = t & 127;
        v = stg[t];
        dst = (size_t)wpack_idx(k, c); ha = wpkhi; la = wpklo;
    } else {
        int u = t - 32768;
        int L = u >> 14, rem = u & 16383;
        int k = rem >> 7, c = rem & 127;
        v = stg[33296 + u];
        dst = (size_t)L * 16384 + wpack_idx(k, c); ha = cwkhi; la = cwklo;
    }
    uint16_t hb = f2bf(v);
    uint16_t lb = f2bf(v - bf2f1(hb));
    ha[dst] = hb; la[dst] = lb;
}

// ---------------- graph prep: atomic-free counting-sort CSR build ----------------

__global__ __launch_bounds__(256) void k_hist(const int* __restrict__ row, int* __restrict__ hist) {
    __shared__ int lh[NBK];
    int b = blockIdx.x, tid = threadIdx.x;
    for (int i = tid; i < NBK; i += 256) lh[i] = 0;
    __syncthreads();
    int e0 = b * CHUNK;
    int lim = N_EDGES - e0; if (lim > CHUNK) lim = CHUNK;
    for (int i = tid; i < lim; i += 256) atomicAdd(&lh[row[e0 + i] >> BSHIFT], 1);
    __syncthreads();
    for (int i = tid; i < NBK; i += 256) hist[(size_t)b * NBK + i] = lh[i];
}

__global__ __launch_bounds__(128) void k_hscan(int* __restrict__ hist, int* __restrict__ totB) {
    __shared__ int s[128];
    int bkt = blockIdx.x, t = threadIdx.x;
    int v = (t < NCH) ? hist[(size_t)t * NBK + bkt] : 0;
    s[t] = v;
    __syncthreads();
    for (int off = 1; off < 128; off <<= 1) {
        int add = (t >= off) ? s[t - off] : 0;
        __syncthreads();
        s[t] += add;
        __syncthreads();
    }
    if (t < NCH) hist[(size_t)t * NBK + bkt] = s[t] - v;   // exclusive within bucket
    if (t == 127) totB[bkt] = s[127];
}

__global__ __launch_bounds__(256) void k_bscan(const int* __restrict__ totB,
                                               int* __restrict__ boffB, int* __restrict__ rp) {
    __shared__ int ps[256];
    int t = threadIdx.x;
    const int STRIP = 7;                     // 256*7 = 1792 >= NBK
    int base = t * STRIP;
    int loc[STRIP]; int sum = 0;
#pragma unroll
    for (int j = 0; j < STRIP; j++) {
        int idx = base + j;
        int v = (idx < NBK) ? totB[idx] : 0;
        loc[j] = sum; sum += v;
    }
    ps[t] = sum;
    __syncthreads();
    int v = ps[t];
    for (int off = 1; off < 256; off <<= 1) {
        int add = (t >= off) ? ps[t - off] : 0;
        __syncthreads();
        ps[t] += add;
        __syncthreads();
    }
    int excl = ps[t] - v;
#pragma unroll
    for (int j = 0; j < STRIP; j++) {
        int idx = base + j;
        if (idx < NBK) boffB[idx] = excl + loc[j];
    }
    if (t == 0) { boffB[NBK] = N_EDGES; rp[N_NODES] = N_EDGES; }
}

__global__ __launch_bounds__(256) void k_sortscat(const int* __restrict__ row, const int* __restrict__ col,
                                                  const int* __restrict__ hist, const int* __restrict__ boffB,
                                                  uint32_t* __restrict__ ebp) {
    __shared__ int dbase[NBK];
    __shared__ int lcnt[NBK];
    int b = blockIdx.x, tid = threadIdx.x;
    for (int i = tid; i < NBK; i += 256) {
        dbase[i] = boffB[i] + hist[(size_t)b * NBK + i];
        lcnt[i] = 0;
    }
    __syncthreads();
    int e0 = b * CHUNK;
    int lim = N_EDGES - e0; if (lim > CHUNK) lim = CHUNK;
    for (int i = tid; i < lim; i += 256) {
        int r = row[e0 + i], c = col[e0 + i];
        int bk = r >> BSHIFT;
        int rank = atomicAdd(&lcnt[bk], 1);
        ebp[dbase[bk] + rank] = ((uint32_t)(r & (BROWS - 1)) << 17) | (uint32_t)c;
    }
}

__global__ __launch_bounds__(256) void k_bfin(const uint32_t* __restrict__ ebp, const int* __restrict__ boffB,
                                              int* __restrict__ rp, float* __restrict__ dis,
                                              int* __restrict__ edc) {
    __shared__ int ldeg[BROWS];
    __shared__ int lcur[BROWS];
    int b = blockIdx.x, tid = threadIdx.x;
    int base = boffB[b];
    int n = boffB[b + 1] - base;
    if (tid < BROWS) ldeg[tid] = 0;
    __syncthreads();
    for (int i = tid; i < n; i += 256) atomicAdd(&ldeg[ebp[base + i] >> 17], 1);
    __syncthreads();
    if (tid == 0) {
        int run = 0;
        for (int r = 0; r < BROWS; r++) { int d = ldeg[r]; lcur[r] = run; run += d; }
    }
    __syncthreads();
    int row0 = b << BSHIFT;
    if (tid < BROWS && row0 + tid < N_NODES) {
        int d = ldeg[tid];
        rp[row0 + tid]  = base + lcur[tid];
        dis[row0 + tid] = rsqrtf((float)(d > 0 ? d : 1));
    }
    __syncthreads();   // rp/dis read lcur before scatter mutates it
    for (int i = tid; i < n; i += 256) {
        uint32_t pk = ebp[base + i];
        int r = pk >> 17;
        int pos = atomicAdd(&lcur[r], 1);
        edc[base + pos] = (int)(pk & 0x1FFFFu);
    }
}

// ---------------- fused SpMM + blend (int16 mirror + per-row scale) ----------------
// Proven config: unroll 8 (VGPR 32, ~70% occupancy). Unroll 16 regressed (m: round 9,
// VGPR 44, occupancy 45%, 73.5 -> 96.7 us) -- do not deepen.

__global__ __launch_bounds__(256) void k_spmm(const uint32_t* __restrict__ Hq,
                                              const float* __restrict__ ScD,
                                              const float* __restrict__ H0,
                                              const int* __restrict__ rp,
                                              const int* __restrict__ edc,
                                              const float* __restrict__ S,
                                              const float* __restrict__ dis,
                                              uint16_t* __restrict__ SupHi,
                                              uint16_t* __restrict__ SupLo) {
    int wid  = (blockIdx.x * 256 + threadIdx.x) >> 6;
    int lane = threadIdx.x & 63;
    if (wid >= N_NODES) return;

    float s  = S[wid];
    float dr = dis[wid];
    float h0x = H0[(size_t)wid * 128 + lane];
    float h0y = H0[(size_t)wid * 128 + 64 + lane];

    int p0 = rp[wid], p1 = rp[wid + 1];
    float ax = 0.f, ay = 0.f;
    int p = p0;
    for (; p + 8 <= p1; p += 8) {
        int c[8]; uint32_t u[8]; float w[8];
#pragma unroll
        for (int j = 0; j < 8; j++) c[j] = edc[p + j];
#pragma unroll
        for (int j = 0; j < 8; j++) u[j] = Hq[(size_t)c[j] * 64 + lane];
#pragma unroll
        for (int j = 0; j < 8; j++) w[j] = ScD[c[j]];
#pragma unroll
        for (int j = 0; j < 8; j++) {
            ax += w[j] * (float)((int)(u[j] << 16) >> 16);
            ay += w[j] * (float)((int)u[j] >> 16);
        }
    }
    for (; p + 4 <= p1; p += 4) {
        int c[4]; uint32_t u[4]; float w[4];
#pragma unroll
        for (int j = 0; j < 4; j++) c[j] = edc[p + j];
#pragma unroll
        for (int j = 0; j < 4; j++) u[j] = Hq[(size_t)c[j] * 64 + lane];
#pragma unroll
        for (int j = 0; j < 4; j++) w[j] = ScD[c[j]];
#pragma unroll
        for (int j = 0; j < 4; j++) {
            ax += w[j] * (float)((int)(u[j] << 16) >> 16);
            ay += w[j] * (float)((int)u[j] >> 16);
        }
    }
    for (; p < p1; p++) {
        int c = edc[p];
        uint32_t u = Hq[(size_t)c * 64 + lane];
        float w = ScD[c];
        ax += w * (float)((int)(u << 16) >> 16);
        ay += w * (float)((int)u >> 16);
    }
    float f = (1.f - s) * dr;
    float ox = f * ax + s * h0x;
    float oy = f * ay + s * h0y;
    uint16_t hx = f2bf(ox), hy = f2bf(oy);
    uint16_t lx = f2bf(ox - bf2f1(hx)), ly = f2bf(oy - bf2f1(hy));
    SupHi[(size_t)wid * 128 + lane]      = hx;
    SupHi[(size_t)wid * 128 + 64 + lane] = hy;
    SupLo[(size_t)wid * 128 + lane]      = lx;
    SupLo[(size_t)wid * 128 + 64 + lane] = ly;
}

// ---------------- MFMA GEMM: W 64-K chunk in LDS (32KB, 3 blk/CU), A in regs ----------
// Block = 128 rows, 4 waves; wave wv owns rows wb=wv*32 + {li, li+16} (two acc sets).
// Per 64-K chunk: stage W hi(+lo) 16(32)KB -> barrier -> barrier-free MFMA loop.
// C layout: col=lane&15, row=(lane>>4)*4+reg (per 16-row set).
// Split products: C = Ah*Wh [+ Al*Wh if A fp32] [+ Ah*Wl if W fp32].
// WQ: epilogue writes Hq int16 pairs + per-row scale Sc (dis-folded) + gate S.
// WC: classifier fused -> writes d_out logits directly (no final h materialized).

template <int KD, int MODE, int WH, int WQ, int WF, int WC>
__global__ __launch_bounds__(256, 3) void k_gemm(
    const void* __restrict__ Ax,
    const uint16_t* __restrict__ Ahi, const uint16_t* __restrict__ Alo,
    const uint16_t* __restrict__ Wh, const uint16_t* __restrict__ Wl,
    const float* __restrict__ bias, const float* __restrict__ gamma,
    const float* __restrict__ beta, const float* __restrict__ qw,
    const float* __restrict__ qb, float theta, const int* __restrict__ flag,
    const float* __restrict__ dis,
    float* __restrict__ Hout, uint32_t* __restrict__ Hq,
    float* __restrict__ Sc, float* __restrict__ S,
    const float* __restrict__ clw, const float* __restrict__ clb,
    void* __restrict__ Out)
{
    if (*flag != WF) return;             // guarded dual-launch fallback
    constexpr int F32A = (MODE == 0) ? WF : 1;   // A has a lo plane
    constexpr int NKB = KD / 64;

    __shared__ __align__(16) uint16_t sWh[8192];   // 16 KiB
    __shared__ __align__(16) uint16_t sWl[8192];   // 16 KiB -> 32 KiB total

    const int tid  = threadIdx.x;
    const int lane = tid & 63;
    const int wv   = tid >> 6;
    const int li   = lane & 15;
    const int lg   = lane >> 4;
    const size_t row0 = (size_t)blockIdx.x * 128;
    const int wb = wv * 32;
    size_t ar0 = row0 + wb + li;      if (ar0 >= N_NODES) ar0 = N_NODES - 1;
    size_t ar1 = row0 + wb + 16 + li; if (ar1 >= N_NODES) ar1 = N_NODES - 1;

    f32x4 acc0[8], acc1[8];
#pragma unroll
    for (int ct = 0; ct < 8; ct++) {
        acc0[ct] = (f32x4){0.f, 0.f, 0.f, 0.f};
        acc1[ct] = (f32x4){0.f, 0.f, 0.f, 0.f};
    }

    for (int kb = 0; kb < NKB; kb++) {
        if (kb) __syncthreads();
        const uint16_t* gh = Wh + kb * 8192;
#pragma unroll
        for (int it = 0; it < 4; it++) {
            int t = tid + it * 256;
            *(uint4*)(sWh + t * 8) = *(const uint4*)(gh + t * 8);
        }
        if constexpr (WF) {
            const uint16_t* gl = Wl + kb * 8192;
#pragma unroll
            for (int it = 0; it < 4; it++) {
                int t = tid + it * 256;
                *(uint4*)(sWl + t * 8) = *(const uint4*)(gl + t * 8);
            }
        }
        bf16x8 a0h[2], a1h[2], a0l[2], a1l[2];
#pragma unroll
        for (int s = 0; s < 2; s++) {
            const int koff = kb * 64 + s * 32 + lg * 8;
            if constexpr (MODE == 1) {
                a0h[s] = *(const bf16x8*)(Ahi + ar0 * KD + koff);
                a0l[s] = *(const bf16x8*)(Alo + ar0 * KD + koff);
                a1h[s] = *(const bf16x8*)(Ahi + ar1 * KD + koff);
                a1l[s] = *(const bf16x8*)(Alo + ar1 * KD + koff);
            } else if constexpr (WF) {
                const float* p0 = (const float*)Ax + ar0 * KD + koff;
                const float* p1 = (const float*)Ax + ar1 * KD + koff;
                float4 u0 = *(const float4*)p0, u1 = *(const float4*)(p0 + 4);
                float4 v0 = *(const float4*)p1, v1 = *(const float4*)(p1 + 4);
                float f0[8] = {u0.x, u0.y, u0.z, u0.w, u1.x, u1.y, u1.z, u1.w};
                float f1[8] = {v0.x, v0.y, v0.z, v0.w, v1.x, v1.y, v1.z, v1.w};
#pragma unroll
                for (int j = 0; j < 8; j++) {
                    uint16_t hb0 = f2bf(f0[j]);
                    a0h[s][j] = (short)hb0;
                    a0l[s][j] = (short)f2bf(f0[j] - bf2f1(hb0));
                    uint16_t hb1 = f2bf(f1[j]);
                    a1h[s][j] = (short)hb1;
                    a1l[s][j] = (short)f2bf(f1[j] - bf2f1(hb1));
                }
            } else {
                a0h[s] = *(const bf16x8*)((const uint16_t*)Ax + ar0 * KD + koff);
                a1h[s] = *(const bf16x8*)((const uint16_t*)Ax + ar1 * KD + koff);
            }
        }
        __syncthreads();
#pragma unroll
        for (int s = 0; s < 2; s++) {
#pragma unroll
            for (int ct = 0; ct < 8; ct++) {
                const int wo = ((s * 8 + ct) * 64 + lane) * 8;
                bf16x8 bh = *(const bf16x8*)(sWh + wo);
                acc0[ct] = __builtin_amdgcn_mfma_f32_16x16x32_bf16(a0h[s], bh, acc0[ct], 0, 0, 0);
                acc1[ct] = __builtin_amdgcn_mfma_f32_16x16x32_bf16(a1h[s], bh, acc1[ct], 0, 0, 0);
                if constexpr (F32A) {
                    acc0[ct] = __builtin_amdgcn_mfma_f32_16x16x32_bf16(a0l[s], bh, acc0[ct], 0, 0, 0);
                    acc1[ct] = __builtin_amdgcn_mfma_f32_16x16x32_bf16(a1l[s], bh, acc1[ct], 0, 0, 0);
                }
                if constexpr (WF) {
                    bf16x8 bl = *(const bf16x8*)(sWl + wo);
                    acc0[ct] = __builtin_amdgcn_mfma_f32_16x16x32_bf16(a0h[s], bl, acc0[ct], 0, 0, 0);
                    acc1[ct] = __builtin_amdgcn_mfma_f32_16x16x32_bf16(a1h[s], bl, acc1[ct], 0, 0, 0);
                }
            }
        }
    }

    // ---- epilogue: per (lane, reg, set) one row, cols {ct*16+li} ----
    float gm[8], bt_[8], qv[8], bi[8];
#pragma unroll
    for (int ct = 0; ct < 8; ct++) {
        int c = ct * 16 + li;
        gm[ct] = gamma[c]; bt_[ct] = beta[c]; qv[ct] = qw[c];
        bi[ct] = (MODE == 0) ? bias[c] : 0.f;
    }
    float wc[WC ? 56 : 1], cb[WC ? 7 : 1];
    if constexpr (WC) {
#pragma unroll
        for (int ct = 0; ct < 8; ct++)
#pragma unroll
            for (int j = 0; j < 7; j++) wc[ct * 7 + j] = clw[(ct * 16 + li) * 7 + j];
#pragma unroll
        for (int j = 0; j < 7; j++) cb[j] = clb[j];
    }
    const float qbv = qb[0];
    const float om  = 1.f - theta;

    auto epi = [&](f32x4 (&acc)[8], int ssoff) {
#pragma unroll
        for (int r = 0; r < 4; r++) {
            int rowl  = wb + ssoff + lg * 4 + r;
            size_t rg = row0 + rowl;
            size_t rc = (rg < N_NODES) ? rg : (N_NODES - 1);
            float v[8];
            if (MODE == 0) {
#pragma unroll
                for (int ct = 0; ct < 8; ct++) v[ct] = acc[ct][r] + bi[ct];
            } else {
#pragma unroll
                for (int ct = 0; ct < 8; ct++) {
                    int c = ct * 16 + li;
                    float sv = bf2f1(Ahi[rc * KD + c]) + bf2f1(Alo[rc * KD + c]);
                    float o  = theta * acc[ct][r] + om * sv;
                    v[ct] = o > 0.f ? o : 0.f;
                }
            }
            float sum = 0.f, sq = 0.f;
#pragma unroll
            for (int ct = 0; ct < 8; ct++) { sum += v[ct]; sq += v[ct] * v[ct]; }
            sum += __shfl_xor(sum, 1); sum += __shfl_xor(sum, 2);
            sum += __shfl_xor(sum, 4); sum += __shfl_xor(sum, 8);
            sq  += __shfl_xor(sq, 1);  sq  += __shfl_xor(sq, 2);
            sq  += __shfl_xor(sq, 4);  sq  += __shfl_xor(sq, 8);
            float mu  = sum * (1.f / 128.f);
            float var = fmaxf(sq * (1.f / 128.f) - mu * mu, 0.f);
            float rs  = rsqrtf(var + LN_EPS);
            float y[8];
#pragma unroll
            for (int ct = 0; ct < 8; ct++) y[ct] = gm[ct] * (v[ct] - mu) * rs + bt_[ct];

            if (WQ) {
                float zd = 0.f, am = 0.f;
#pragma unroll
                for (int ct = 0; ct < 8; ct++) { zd += y[ct] * qv[ct]; am = fmaxf(am, fabsf(y[ct])); }
                zd += __shfl_xor(zd, 1); zd += __shfl_xor(zd, 2);
                zd += __shfl_xor(zd, 4); zd += __shfl_xor(zd, 8);
                am = fmaxf(am, __shfl_xor(am, 1)); am = fmaxf(am, __shfl_xor(am, 2));
                am = fmaxf(am, __shfl_xor(am, 4)); am = fmaxf(am, __shfl_xor(am, 8));
                float amc  = fmaxf(am, 1e-20f);
                float qinv = 32767.f / amc;
                if (rg < N_NODES) {
                    uint32_t* mq = Hq + rg * 64;
#pragma unroll
                    for (int ct = 0; ct < 4; ct++)
                        mq[ct * 16 + li] = packq(y[ct], y[ct + 4], qinv);  // pair (c, c+64)
                    if (li == 0) {
                        Sc[rg] = amc * (1.f / 32767.f) * dis[rg];   // fold dis[col] into scale
                        S[rg]  = 1.f / (1.f + __expf(-(zd + qbv - 1.f)));
                    }
                }
            }
            if (WH && rg < N_NODES) {
                float* dst = Hout + rg * 128;
#pragma unroll
                for (int ct = 0; ct < 8; ct++) dst[ct * 16 + li] = y[ct];
            }
            if (WC && rg < N_NODES) {
#pragma unroll
                for (int j = 0; j < 7; j++) {
                    float z = 0.f;
#pragma unroll
                    for (int ct = 0; ct < 8; ct++) z += y[ct] * wc[ct * 7 + j];
                    z += __shfl_xor(z, 1); z += __shfl_xor(z, 2);
                    z += __shfl_xor(z, 4); z += __shfl_xor(z, 8);
                    if (li == j) {
                        size_t oi = rg * OUT_DIM + j;
                        if (WF) ((float*)Out)[oi] = z + cb[j];
                        else    ((uint16_t*)Out)[oi] = f2bf(z + cb[j]);
                    }
                }
            }
        }
    };
    epi(acc0, 0);
    epi(acc1, 16);
}

// ---------------- launch ----------------

extern "C" void kernel_launch(void* const* d_in, const int* in_sizes, int n_in,
                              void* d_out, int out_size, void* d_ws, size_t ws_size,
                              hipStream_t stream) {
    const void* x_raw = d_in[0];
    const int*  ei    = (const int*)d_in[1];
    const int* row = ei;
    const int* col = ei + N_EDGES;

    char* ws = (char*)d_ws;
    size_t off = 0;
    auto alloc = [&](size_t b) { void* p = ws + off; off = (off + b + 255) & ~(size_t)255; return p; };
    int*      flag = (int*)alloc(4);
    float*    stgf = (float*)alloc((size_t)99744 * 4);
    int*      rp   = (int*)alloc(((size_t)N_NODES + 1) * 4);
    float*    dis  = (float*)alloc((size_t)N_NODES * 4);
    int*      hist = (int*)alloc((size_t)NCH * NBK * 4);
    int*      totB = (int*)alloc((size_t)NBK * 4);
    int*      boffB= (int*)alloc(((size_t)NBK + 1) * 4);
    int*      edc  = (int*)alloc((size_t)N_EDGES * 4);             // CSR cols (4B)
    float*    h0   = (float*)alloc((size_t)N_NODES * HID * 4);     // h0 (spmm blend input)
    uint16_t* suphi= (uint16_t*)alloc((size_t)N_NODES * HID * 2);  // support hi plane
    uint16_t* suplo= (uint16_t*)alloc((size_t)N_NODES * HID * 2);  // support lo plane
    uint32_t* hq   = (uint32_t*)alloc((size_t)N_NODES * 64 * 4);   // int16 mirror
    float*    Scq  = (float*)alloc((size_t)N_NODES * 4);           // quant scale * dis
    float*    Sg   = (float*)alloc((size_t)N_NODES * 4);           // gate sigmoid
    uint16_t* wpkhi = (uint16_t*)alloc((size_t)32768 * 2);         // W_proj packed hi
    uint16_t* wpklo = (uint16_t*)alloc((size_t)32768 * 2);
    uint16_t* cwkhi = (uint16_t*)alloc((size_t)65536 * 2);         // conv_w packed hi (4 layers)
    uint16_t* cwklo = (uint16_t*)alloc((size_t)65536 * 2);
    uint32_t* ebp  = (uint32_t*)h0;   // bucket-sorted packed edges (6.4MB) alias h0

    const float* bp  = stgf + 32768;
    const float* gm  = stgf + 32896;
    const float* bt  = stgf + 33024;
    const float* qw  = stgf + 33152;
    const float* qb  = stgf + 33280;
    const float* clw = stgf + 98832;
    const float* clb = stgf + 99728;

    // host-side dtype detection from byte sizes; -1 = unknown -> guarded dual launch
    int hostflag = -1;
    if (in_sizes && n_in >= 3) {
        if      (in_sizes[2] == 32768 * 4) hostflag = 1;
        else if (in_sizes[2] == 32768 * 2) hostflag = 0;
        else if (in_sizes[0] == N_NODES * IN_DIM * 4) hostflag = 1;
        else if (in_sizes[0] == N_NODES * IN_DIM * 2) hostflag = 0;
    }
    if (hostflag >= 0) k_setflag<<<1, 64, 0, stream>>>(flag, hostflag);
    else               k_detect<<<1, 64, 0, stream>>>((const uint32_t*)d_in[2], flag);

    k_cvt<<<(99720 + 255) / 256, 256, 0, stream>>>(d_in[2], d_in[3], d_in[4], d_in[5], d_in[6],
                                                   d_in[7], d_in[8], d_in[9], d_in[10], stgf, flag);
    k_wsplit<<<(98304 + 255) / 256, 256, 0, stream>>>(stgf, wpkhi, wpklo, cwkhi, cwklo);

    k_hist<<<NCH, 256, 0, stream>>>(row, hist);
    k_hscan<<<NBK, 128, 0, stream>>>(hist, totB);
    k_bscan<<<1, 256, 0, stream>>>(totB, boffB, rp);
    k_sortscat<<<NCH, 256, 0, stream>>>(row, col, hist, boffB, ebp);
    k_bfin<<<NBK, 256, 0, stream>>>(ebp, boffB, rp, dis, edc);

    const int gg = (N_NODES + 127) / 128;   // 782
    if (hostflag != 0)
        k_gemm<IN_DIM, 0, 1, 1, 1, 0><<<gg, 256, 0, stream>>>(
            x_raw, nullptr, nullptr, wpkhi, wpklo, bp, gm, bt, qw, qb, 0.f, flag, dis,
            h0, hq, Scq, Sg, clw, clb, d_out);
    if (hostflag != 1)
        k_gemm<IN_DIM, 0, 1, 1, 0, 0><<<gg, 256, 0, stream>>>(
            x_raw, nullptr, nullptr, wpkhi, wpklo, bp, gm, bt, qw, qb, 0.f, flag, dis,
            h0, hq, Scq, Sg, clw, clb, d_out);

    for (int i = 0; i < N_LAYERS; i++) {
        k_spmm<<<(N_NODES + 3) / 4, 256, 0, stream>>>(hq, Scq, h0, rp, edc, Sg, dis, suphi, suplo);
        float theta = 0.5f / (float)(i + 1);
        const uint16_t* whi = cwkhi + (size_t)i * 16384;
        const uint16_t* wlo = cwklo + (size_t)i * 16384;
        if (i < N_LAYERS - 1) {
            if (hostflag != 0)
                k_gemm<HID, 1, 0, 1, 1, 0><<<gg, 256, 0, stream>>>(
                    nullptr, suphi, suplo, whi, wlo, nullptr, gm, bt, qw, qb, theta, flag, dis,
                    nullptr, hq, Scq, Sg, clw, clb, d_out);
            if (hostflag != 1)
                k_gemm<HID, 1, 0, 1, 0, 0><<<gg, 256, 0, stream>>>(
                    nullptr, suphi, suplo, whi, wlo, nullptr, gm, bt, qw, qb, theta, flag, dis,
                    nullptr, hq, Scq, Sg, clw, clb, d_out);
        } else {
            // last layer: classifier fused, no final h materialized
            if (hostflag != 0)
                k_gemm<HID, 1, 0, 0, 1, 1><<<gg, 256, 0, stream>>>(
                    nullptr, suphi, suplo, whi, wlo, nullptr, gm, bt, qw, qb, theta, flag, dis,
                    nullptr, hq, Scq, Sg, clw, clb, d_out);
            if (hostflag != 1)
                k_gemm<HID, 1, 0, 0, 0, 1><<<gg, 256, 0, stream>>>(
                    nullptr, suphi, suplo, whi, wlo, nullptr, gm, bt, qw, qb, theta, flag, dis,
                    nullptr, hq, Scq, Sg, clw, clb, d_out);
        }
    }
}

// Round 11
// 759.820 us; speedup vs baseline: 1.0953x; 1.0010x over previous
//
#include <hip/hip_runtime.h>
#include <hip/hip_bf16.h>
#include <hip/hip_fp16.h>
#include <stdint.h>

#define N_NODES 100000
#define N_EDGES 1600000
#define IN_DIM 256
#define HID 128
#define N_LAYERS 4
#define OUT_DIM 7
#define LN_EPS 1e-5f

// counting-sort CSR build
#define BSHIFT 6
#define BROWS 64
#define NBK 1563                  // ceil(100000/64) buckets of 64 rows
#define CHUNK 16384               // edges per sort block
#define NCH ((N_EDGES + CHUNK - 1) / CHUNK)   // 98 (must be <= 128 for k_hscan)

typedef __attribute__((ext_vector_type(8))) short bf16x8;
typedef __attribute__((ext_vector_type(4))) float f32x4;

__device__ inline float bf2f1(uint16_t u) {
    union { uint32_t i; float f; } a; a.i = ((uint32_t)u) << 16; return a.f;
}
__device__ inline uint16_t f2bf(float f) {
    union { float f; uint32_t i; } a; a.f = f;
    uint32_t lsb = (a.i >> 16) & 1u;
    a.i += 0x7fffu + lsb;          // round-to-nearest-even
    return (uint16_t)(a.i >> 16);
}
__device__ inline uint32_t packq(float a, float b, float qinv) {
    int qa = __float2int_rn(a * qinv);
    int qb = __float2int_rn(b * qinv);
    return ((uint32_t)(uint16_t)(short)qa) | (((uint32_t)(uint16_t)(short)qb) << 16);
}

// fragment-order W pack: lane-linear so LDS B-frag read is one contiguous 16B.
// element (k, c) of W[KD][128] -> ((ksg*8 + ct)*64 + lane)*8 + e
__device__ __host__ inline int wpack_idx(int k, int c) {
    int ksg = k >> 5, lg = (k >> 3) & 3, e = k & 7;
    int ct = c >> 4, li = c & 15;
    return ((ksg * 8 + ct) * 64 + (lg * 16 + li)) * 8 + e;
}

// ---------------- dtype detection ----------------
__global__ void k_detect(const uint32_t* __restrict__ W, int* __restrict__ flag) {
    if (threadIdx.x == 0 && blockIdx.x == 0) {
        int cnt = 0;
        for (int i = 0; i < 64; i++) {
            uint32_t lo = W[i] & 0xffffu;
            uint32_t ex = (lo >> 7) & 0xff;
            if (ex >= 0x60 && ex < 0x7c) cnt++;
        }
        *flag = (cnt < 32) ? 1 : 0;   // 1 = fp32 inputs, 0 = bf16 inputs
    }
}
__global__ void k_setflag(int* __restrict__ flag, int v) {
    if (threadIdx.x == 0) *flag = v;
}

// ---------------- weight canonicalization (all weights -> fp32 staged) ----------------
__global__ __launch_bounds__(256) void k_cvt(const void* a0, const void* a1, const void* a2,
                                             const void* a3, const void* a4, const void* a5,
                                             const void* a6, const void* a7, const void* a8,
                                             float* __restrict__ dst, const int* __restrict__ flag) {
    int t = blockIdx.x * 256 + threadIdx.x;
    if (t >= 99720) return;
    const void* src; int i; int off;
    if      (t < 32768) { src = a0; i = t;         off = 0;     }   // W_proj 256x128
    else if (t < 32896) { src = a1; i = t - 32768; off = 32768; }   // b_proj 128
    else if (t < 33024) { src = a2; i = t - 32896; off = 32896; }   // gamma 128
    else if (t < 33152) { src = a3; i = t - 33024; off = 33024; }   // beta 128
    else if (t < 33280) { src = a4; i = t - 33152; off = 33152; }   // q_w 128
    else if (t < 33281) { src = a5; i = t - 33280; off = 33280; }   // q_b 1
    else if (t < 98817) { src = a6; i = t - 33281; off = 33296; }   // conv_w 4x128x128
    else if (t < 99713) { src = a7; i = t - 98817; off = 98832; }   // cls_w 128x7
    else                { src = a8; i = t - 99713; off = 99728; }   // cls_b 7
    float v;
    if (*flag) v = ((const float*)src)[i];
    else       v = bf2f1(((const uint16_t*)src)[i]);
    dst[off + i] = v;
}

// ---------------- split-bf16 weight prep, fragment/lane-ordered ----------------
__global__ __launch_bounds__(256) void k_wsplit(const float* __restrict__ stg,
                                                uint16_t* __restrict__ wpkhi, uint16_t* __restrict__ wpklo,
                                                uint16_t* __restrict__ cwkhi, uint16_t* __restrict__ cwklo) {
    int t = blockIdx.x * 256 + threadIdx.x;
    if (t >= 32768 + 65536) return;
    float v; size_t dst; uint16_t *ha, *la;
    if (t < 32768) {
        int k = t >> 7, c = t & 127;
        v = stg[t];
        dst = (size_t)wpack_idx(k, c); ha = wpkhi; la = wpklo;
    } else {
        int u = t - 32768;
        int L = u >> 14, rem = u & 16383;
        int k = rem >> 7, c = rem & 127;
        v = stg[33296 + u];
        dst = (size_t)L * 16384 + wpack_idx(k, c); ha = cwkhi; la = cwklo;
    }
    uint16_t hb = f2bf(v);
    uint16_t lb = f2bf(v - bf2f1(hb));
    ha[dst] = hb; la[dst] = lb;
}

// ---------------- graph prep: atomic-free counting-sort CSR build ----------------

__global__ __launch_bounds__(256) void k_hist(const int* __restrict__ row, int* __restrict__ hist) {
    __shared__ int lh[NBK];
    int b = blockIdx.x, tid = threadIdx.x;
    for (int i = tid; i < NBK; i += 256) lh[i] = 0;
    __syncthreads();
    int e0 = b * CHUNK;
    int lim = N_EDGES - e0; if (lim > CHUNK) lim = CHUNK;
    for (int i = tid; i < lim; i += 256) atomicAdd(&lh[row[e0 + i] >> BSHIFT], 1);
    __syncthreads();
    for (int i = tid; i < NBK; i += 256) hist[(size_t)b * NBK + i] = lh[i];
}

__global__ __launch_bounds__(128) void k_hscan(int* __restrict__ hist, int* __restrict__ totB) {
    __shared__ int s[128];
    int bkt = blockIdx.x, t = threadIdx.x;
    int v = (t < NCH) ? hist[(size_t)t * NBK + bkt] : 0;
    s[t] = v;
    __syncthreads();
    for (int off = 1; off < 128; off <<= 1) {
        int add = (t >= off) ? s[t - off] : 0;
        __syncthreads();
        s[t] += add;
        __syncthreads();
    }
    if (t < NCH) hist[(size_t)t * NBK + bkt] = s[t] - v;   // exclusive within bucket
    if (t == 127) totB[bkt] = s[127];
}

__global__ __launch_bounds__(256) void k_bscan(const int* __restrict__ totB,
                                               int* __restrict__ boffB, int* __restrict__ rp) {
    __shared__ int ps[256];
    int t = threadIdx.x;
    const int STRIP = 7;                     // 256*7 = 1792 >= NBK
    int base = t * STRIP;
    int loc[STRIP]; int sum = 0;
#pragma unroll
    for (int j = 0; j < STRIP; j++) {
        int idx = base + j;
        int v = (idx < NBK) ? totB[idx] : 0;
        loc[j] = sum; sum += v;
    }
    ps[t] = sum;
    __syncthreads();
    int v = ps[t];
    for (int off = 1; off < 256; off <<= 1) {
        int add = (t >= off) ? ps[t - off] : 0;
        __syncthreads();
        ps[t] += add;
        __syncthreads();
    }
    int excl = ps[t] - v;
#pragma unroll
    for (int j = 0; j < STRIP; j++) {
        int idx = base + j;
        if (idx < NBK) boffB[idx] = excl + loc[j];
    }
    if (t == 0) { boffB[NBK] = N_EDGES; rp[N_NODES] = N_EDGES; }
}

__global__ __launch_bounds__(256) void k_sortscat(const int* __restrict__ row, const int* __restrict__ col,
                                                  const int* __restrict__ hist, const int* __restrict__ boffB,
                                                  uint32_t* __restrict__ ebp) {
    __shared__ int dbase[NBK];
    __shared__ int lcnt[NBK];
    int b = blockIdx.x, tid = threadIdx.x;
    for (int i = tid; i < NBK; i += 256) {
        dbase[i] = boffB[i] + hist[(size_t)b * NBK + i];
        lcnt[i] = 0;
    }
    __syncthreads();
    int e0 = b * CHUNK;
    int lim = N_EDGES - e0; if (lim > CHUNK) lim = CHUNK;
    for (int i = tid; i < lim; i += 256) {
        int r = row[e0 + i], c = col[e0 + i];
        int bk = r >> BSHIFT;
        int rank = atomicAdd(&lcnt[bk], 1);
        ebp[dbase[bk] + rank] = ((uint32_t)(r & (BROWS - 1)) << 17) | (uint32_t)c;
    }
}

__global__ __launch_bounds__(256) void k_bfin(const uint32_t* __restrict__ ebp, const int* __restrict__ boffB,
                                              int* __restrict__ rp, float* __restrict__ dis,
                                              int* __restrict__ edc) {
    __shared__ int ldeg[BROWS];
    __shared__ int lcur[BROWS];
    int b = blockIdx.x, tid = threadIdx.x;
    int base = boffB[b];
    int n = boffB[b + 1] - base;
    if (tid < BROWS) ldeg[tid] = 0;
    __syncthreads();
    for (int i = tid; i < n; i += 256) atomicAdd(&ldeg[ebp[base + i] >> 17], 1);
    __syncthreads();
    if (tid == 0) {
        int run = 0;
        for (int r = 0; r < BROWS; r++) { int d = ldeg[r]; lcur[r] = run; run += d; }
    }
    __syncthreads();
    int row0 = b << BSHIFT;
    if (tid < BROWS && row0 + tid < N_NODES) {
        int d = ldeg[tid];
        rp[row0 + tid]  = base + lcur[tid];
        dis[row0 + tid] = rsqrtf((float)(d > 0 ? d : 1));
    }
    __syncthreads();   // rp/dis read lcur before scatter mutates it
    for (int i = tid; i < n; i += 256) {
        uint32_t pk = ebp[base + i];
        int r = pk >> 17;
        int pos = atomicAdd(&lcur[r], 1);
        edc[base + pos] = (int)(pk & 0x1FFFFu);
    }
}

// ---------------- fused SpMM + blend (int16 mirror + per-row scale) ----------------
// Proven config: unroll 8 (VGPR 32, ~70% occ, 73.5us). Unroll 16 regressed (round 9:
// VGPR 44, occ 45%, 96.7us) -- do not deepen.

__global__ __launch_bounds__(256) void k_spmm(const uint32_t* __restrict__ Hq,
                                              const float* __restrict__ ScD,
                                              const float* __restrict__ H0,
                                              const int* __restrict__ rp,
                                              const int* __restrict__ edc,
                                              const float* __restrict__ S,
                                              const float* __restrict__ dis,
                                              uint16_t* __restrict__ SupHi,
                                              uint16_t* __restrict__ SupLo) {
    int wid  = (blockIdx.x * 256 + threadIdx.x) >> 6;
    int lane = threadIdx.x & 63;
    if (wid >= N_NODES) return;

    float s  = S[wid];
    float dr = dis[wid];
    float h0x = H0[(size_t)wid * 128 + lane];
    float h0y = H0[(size_t)wid * 128 + 64 + lane];

    int p0 = rp[wid], p1 = rp[wid + 1];
    float ax = 0.f, ay = 0.f;
    int p = p0;
    for (; p + 8 <= p1; p += 8) {
        int c[8]; uint32_t u[8]; float w[8];
#pragma unroll
        for (int j = 0; j < 8; j++) c[j] = edc[p + j];
#pragma unroll
        for (int j = 0; j < 8; j++) u[j] = Hq[(size_t)c[j] * 64 + lane];
#pragma unroll
        for (int j = 0; j < 8; j++) w[j] = ScD[c[j]];
#pragma unroll
        for (int j = 0; j < 8; j++) {
            ax += w[j] * (float)((int)(u[j] << 16) >> 16);
            ay += w[j] * (float)((int)u[j] >> 16);
        }
    }
    for (; p + 4 <= p1; p += 4) {
        int c[4]; uint32_t u[4]; float w[4];
#pragma unroll
        for (int j = 0; j < 4; j++) c[j] = edc[p + j];
#pragma unroll
        for (int j = 0; j < 4; j++) u[j] = Hq[(size_t)c[j] * 64 + lane];
#pragma unroll
        for (int j = 0; j < 4; j++) w[j] = ScD[c[j]];
#pragma unroll
        for (int j = 0; j < 4; j++) {
            ax += w[j] * (float)((int)(u[j] << 16) >> 16);
            ay += w[j] * (float)((int)u[j] >> 16);
        }
    }
    for (; p < p1; p++) {
        int c = edc[p];
        uint32_t u = Hq[(size_t)c * 64 + lane];
        float w = ScD[c];
        ax += w * (float)((int)(u << 16) >> 16);
        ay += w * (float)((int)u >> 16);
    }
    float f = (1.f - s) * dr;
    float ox = f * ax + s * h0x;
    float oy = f * ay + s * h0y;
    uint16_t hx = f2bf(ox), hy = f2bf(oy);
    uint16_t lx = f2bf(ox - bf2f1(hx)), ly = f2bf(oy - bf2f1(hy));
    SupHi[(size_t)wid * 128 + lane]      = hx;
    SupHi[(size_t)wid * 128 + 64 + lane] = hy;
    SupLo[(size_t)wid * 128 + lane]      = lx;
    SupLo[(size_t)wid * 128 + 64 + lane] = ly;
}

// ---------------- MFMA GEMM: W 128-K chunk in LDS (64KB, 2 blk/CU), A in regs --------
// REVERTED to round-6 chunking: 64-K chunks (round 7-10) regressed MODE-0 73->97us
// (doubled barriers, halved per-barrier A-preload latency cover; occupancy gain never
// materialized -- 25% measured vs 37.5% cap). 128-K chunk = proven <73.5us.
// Block = 128 rows, 4 waves; wave wv owns rows wb=wv*32 + {li, li+16} (two acc sets).
// Per 128-K chunk: stage W hi(+lo) 32(64)KB once -> barrier -> barrier-free MFMA loop.
// C layout: col=lane&15, row=(lane>>4)*4+reg (per 16-row set).
// Split products: C = Ah*Wh [+ Al*Wh if A fp32] [+ Ah*Wl if W fp32].
// WQ: epilogue writes Hq int16 pairs + per-row scale Sc (dis-folded) + gate S.
// WC: classifier fused -> writes d_out logits directly (no final h materialized).

template <int KD, int MODE, int WH, int WQ, int WF, int WC>
__global__ __launch_bounds__(256, 2) void k_gemm(
    const void* __restrict__ Ax,
    const uint16_t* __restrict__ Ahi, const uint16_t* __restrict__ Alo,
    const uint16_t* __restrict__ Wh, const uint16_t* __restrict__ Wl,
    const float* __restrict__ bias, const float* __restrict__ gamma,
    const float* __restrict__ beta, const float* __restrict__ qw,
    const float* __restrict__ qb, float theta, const int* __restrict__ flag,
    const float* __restrict__ dis,
    float* __restrict__ Hout, uint32_t* __restrict__ Hq,
    float* __restrict__ Sc, float* __restrict__ S,
    const float* __restrict__ clw, const float* __restrict__ clb,
    void* __restrict__ Out)
{
    if (*flag != WF) return;             // guarded dual-launch fallback
    constexpr int F32A = (MODE == 0) ? WF : 1;   // A has a lo plane
    constexpr int NKB = KD / 128;

    __shared__ __align__(16) uint16_t sWh[16384];   // 32 KiB
    __shared__ __align__(16) uint16_t sWl[16384];   // 32 KiB -> 64 KiB total

    const int tid  = threadIdx.x;
    const int lane = tid & 63;
    const int wv   = tid >> 6;
    const int li   = lane & 15;
    const int lg   = lane >> 4;
    const size_t row0 = (size_t)blockIdx.x * 128;
    const int wb = wv * 32;
    size_t ar0 = row0 + wb + li;      if (ar0 >= N_NODES) ar0 = N_NODES - 1;
    size_t ar1 = row0 + wb + 16 + li; if (ar1 >= N_NODES) ar1 = N_NODES - 1;

    f32x4 acc0[8], acc1[8];
#pragma unroll
    for (int ct = 0; ct < 8; ct++) {
        acc0[ct] = (f32x4){0.f, 0.f, 0.f, 0.f};
        acc1[ct] = (f32x4){0.f, 0.f, 0.f, 0.f};
    }

    for (int kb = 0; kb < NKB; kb++) {
        if (kb) __syncthreads();
        const uint16_t* gh = Wh + kb * 16384;
#pragma unroll
        for (int it = 0; it < 8; it++) {
            int t = tid + it * 256;
            *(uint4*)(sWh + t * 8) = *(const uint4*)(gh + t * 8);
        }
        if constexpr (WF) {
            const uint16_t* gl = Wl + kb * 16384;
#pragma unroll
            for (int it = 0; it < 8; it++) {
                int t = tid + it * 256;
                *(uint4*)(sWl + t * 8) = *(const uint4*)(gl + t * 8);
            }
        }
        bf16x8 a0h[4], a1h[4], a0l[4], a1l[4];
#pragma unroll
        for (int s = 0; s < 4; s++) {
            const int koff = kb * 128 + s * 32 + lg * 8;
            if constexpr (MODE == 1) {
                a0h[s] = *(const bf16x8*)(Ahi + ar0 * KD + koff);
                a0l[s] = *(const bf16x8*)(Alo + ar0 * KD + koff);
                a1h[s] = *(const bf16x8*)(Ahi + ar1 * KD + koff);
                a1l[s] = *(const bf16x8*)(Alo + ar1 * KD + koff);
            } else if constexpr (WF) {
                const float* p0 = (const float*)Ax + ar0 * KD + koff;
                const float* p1 = (const float*)Ax + ar1 * KD + koff;
                float4 u0 = *(const float4*)p0, u1 = *(const float4*)(p0 + 4);
                float4 v0 = *(const float4*)p1, v1 = *(const float4*)(p1 + 4);
                float f0[8] = {u0.x, u0.y, u0.z, u0.w, u1.x, u1.y, u1.z, u1.w};
                float f1[8] = {v0.x, v0.y, v0.z, v0.w, v1.x, v1.y, v1.z, v1.w};
#pragma unroll
                for (int j = 0; j < 8; j++) {
                    uint16_t hb0 = f2bf(f0[j]);
                    a0h[s][j] = (short)hb0;
                    a0l[s][j] = (short)f2bf(f0[j] - bf2f1(hb0));
                    uint16_t hb1 = f2bf(f1[j]);
                    a1h[s][j] = (short)hb1;
                    a1l[s][j] = (short)f2bf(f1[j] - bf2f1(hb1));
                }
            } else {
                a0h[s] = *(const bf16x8*)((const uint16_t*)Ax + ar0 * KD + koff);
                a1h[s] = *(const bf16x8*)((const uint16_t*)Ax + ar1 * KD + koff);
            }
        }
        __syncthreads();
#pragma unroll
        for (int s = 0; s < 4; s++) {
#pragma unroll
            for (int ct = 0; ct < 8; ct++) {
                const int wo = ((s * 8 + ct) * 64 + lane) * 8;
                bf16x8 bh = *(const bf16x8*)(sWh + wo);
                acc0[ct] = __builtin_amdgcn_mfma_f32_16x16x32_bf16(a0h[s], bh, acc0[ct], 0, 0, 0);
                acc1[ct] = __builtin_amdgcn_mfma_f32_16x16x32_bf16(a1h[s], bh, acc1[ct], 0, 0, 0);
                if constexpr (F32A) {
                    acc0[ct] = __builtin_amdgcn_mfma_f32_16x16x32_bf16(a0l[s], bh, acc0[ct], 0, 0, 0);
                    acc1[ct] = __builtin_amdgcn_mfma_f32_16x16x32_bf16(a1l[s], bh, acc1[ct], 0, 0, 0);
                }
                if constexpr (WF) {
                    bf16x8 bl = *(const bf16x8*)(sWl + wo);
                    acc0[ct] = __builtin_amdgcn_mfma_f32_16x16x32_bf16(a0h[s], bl, acc0[ct], 0, 0, 0);
                    acc1[ct] = __builtin_amdgcn_mfma_f32_16x16x32_bf16(a1h[s], bl, acc1[ct], 0, 0, 0);
                }
            }
        }
    }

    // ---- epilogue: per (lane, reg, set) one row, cols {ct*16+li} ----
    float gm[8], bt_[8], qv[8], bi[8];
#pragma unroll
    for (int ct = 0; ct < 8; ct++) {
        int c = ct * 16 + li;
        gm[ct] = gamma[c]; bt_[ct] = beta[c]; qv[ct] = qw[c];
        bi[ct] = (MODE == 0) ? bias[c] : 0.f;
    }
    float wc[WC ? 56 : 1], cb[WC ? 7 : 1];
    if constexpr (WC) {
#pragma unroll
        for (int ct = 0; ct < 8; ct++)
#pragma unroll
            for (int j = 0; j < 7; j++) wc[ct * 7 + j] = clw[(ct * 16 + li) * 7 + j];
#pragma unroll
        for (int j = 0; j < 7; j++) cb[j] = clb[j];
    }
    const float qbv = qb[0];
    const float om  = 1.f - theta;

    auto epi = [&](f32x4 (&acc)[8], int ssoff) {
#pragma unroll
        for (int r = 0; r < 4; r++) {
            int rowl  = wb + ssoff + lg * 4 + r;
            size_t rg = row0 + rowl;
            size_t rc = (rg < N_NODES) ? rg : (N_NODES - 1);
            float v[8];
            if (MODE == 0) {
#pragma unroll
                for (int ct = 0; ct < 8; ct++) v[ct] = acc[ct][r] + bi[ct];
            } else {
#pragma unroll
                for (int ct = 0; ct < 8; ct++) {
                    int c = ct * 16 + li;
                    float sv = bf2f1(Ahi[rc * KD + c]) + bf2f1(Alo[rc * KD + c]);
                    float o  = theta * acc[ct][r] + om * sv;
                    v[ct] = o > 0.f ? o : 0.f;
                }
            }
            float sum = 0.f, sq = 0.f;
#pragma unroll
            for (int ct = 0; ct < 8; ct++) { sum += v[ct]; sq += v[ct] * v[ct]; }
            sum += __shfl_xor(sum, 1); sum += __shfl_xor(sum, 2);
            sum += __shfl_xor(sum, 4); sum += __shfl_xor(sum, 8);
            sq  += __shfl_xor(sq, 1);  sq  += __shfl_xor(sq, 2);
            sq  += __shfl_xor(sq, 4);  sq  += __shfl_xor(sq, 8);
            float mu  = sum * (1.f / 128.f);
            float var = fmaxf(sq * (1.f / 128.f) - mu * mu, 0.f);
            float rs  = rsqrtf(var + LN_EPS);
            float y[8];
#pragma unroll
            for (int ct = 0; ct < 8; ct++) y[ct] = gm[ct] * (v[ct] - mu) * rs + bt_[ct];

            if (WQ) {
                float zd = 0.f, am = 0.f;
#pragma unroll
                for (int ct = 0; ct < 8; ct++) { zd += y[ct] * qv[ct]; am = fmaxf(am, fabsf(y[ct])); }
                zd += __shfl_xor(zd, 1); zd += __shfl_xor(zd, 2);
                zd += __shfl_xor(zd, 4); zd += __shfl_xor(zd, 8);
                am = fmaxf(am, __shfl_xor(am, 1)); am = fmaxf(am, __shfl_xor(am, 2));
                am = fmaxf(am, __shfl_xor(am, 4)); am = fmaxf(am, __shfl_xor(am, 8));
                float amc  = fmaxf(am, 1e-20f);
                float qinv = 32767.f / amc;
                if (rg < N_NODES) {
                    uint32_t* mq = Hq + rg * 64;
#pragma unroll
                    for (int ct = 0; ct < 4; ct++)
                        mq[ct * 16 + li] = packq(y[ct], y[ct + 4], qinv);  // pair (c, c+64)
                    if (li == 0) {
                        Sc[rg] = amc * (1.f / 32767.f) * dis[rg];   // fold dis[col] into scale
                        S[rg]  = 1.f / (1.f + __expf(-(zd + qbv - 1.f)));
                    }
                }
            }
            if (WH && rg < N_NODES) {
                float* dst = Hout + rg * 128;
#pragma unroll
                for (int ct = 0; ct < 8; ct++) dst[ct * 16 + li] = y[ct];
            }
            if (WC && rg < N_NODES) {
#pragma unroll
                for (int j = 0; j < 7; j++) {
                    float z = 0.f;
#pragma unroll
                    for (int ct = 0; ct < 8; ct++) z += y[ct] * wc[ct * 7 + j];
                    z += __shfl_xor(z, 1); z += __shfl_xor(z, 2);
                    z += __shfl_xor(z, 4); z += __shfl_xor(z, 8);
                    if (li == j) {
                        size_t oi = rg * OUT_DIM + j;
                        if (WF) ((float*)Out)[oi] = z + cb[j];
                        else    ((uint16_t*)Out)[oi] = f2bf(z + cb[j]);
                    }
                }
            }
        }
    };
    epi(acc0, 0);
    epi(acc1, 16);
}

// ---------------- launch ----------------

extern "C" void kernel_launch(void* const* d_in, const int* in_sizes, int n_in,
                              void* d_out, int out_size, void* d_ws, size_t ws_size,
                              hipStream_t stream) {
    const void* x_raw = d_in[0];
    const int*  ei    = (const int*)d_in[1];
    const int* row = ei;
    const int* col = ei + N_EDGES;

    char* ws = (char*)d_ws;
    size_t off = 0;
    auto alloc = [&](size_t b) { void* p = ws + off; off = (off + b + 255) & ~(size_t)255; return p; };
    int*      flag = (int*)alloc(4);
    float*    stgf = (float*)alloc((size_t)99744 * 4);
    int*      rp   = (int*)alloc(((size_t)N_NODES + 1) * 4);
    float*    dis  = (float*)alloc((size_t)N_NODES * 4);
    int*      hist = (int*)alloc((size_t)NCH * NBK * 4);
    int*      totB = (int*)alloc((size_t)NBK * 4);
    int*      boffB= (int*)alloc(((size_t)NBK + 1) * 4);
    int*      edc  = (int*)alloc((size_t)N_EDGES * 4);             // CSR cols (4B)
    float*    h0   = (float*)alloc((size_t)N_NODES * HID * 4);     // h0 (spmm blend input)
    uint16_t* suphi= (uint16_t*)alloc((size_t)N_NODES * HID * 2);  // support hi plane
    uint16_t* suplo= (uint16_t*)alloc((size_t)N_NODES * HID * 2);  // support lo plane
    uint32_t* hq   = (uint32_t*)alloc((size_t)N_NODES * 64 * 4);   // int16 mirror
    float*    Scq  = (float*)alloc((size_t)N_NODES * 4);           // quant scale * dis
    float*    Sg   = (float*)alloc((size_t)N_NODES * 4);           // gate sigmoid
    uint16_t* wpkhi = (uint16_t*)alloc((size_t)32768 * 2);         // W_proj packed hi
    uint16_t* wpklo = (uint16_t*)alloc((size_t)32768 * 2);
    uint16_t* cwkhi = (uint16_t*)alloc((size_t)65536 * 2);         // conv_w packed hi (4 layers)
    uint16_t* cwklo = (uint16_t*)alloc((size_t)65536 * 2);
    uint32_t* ebp  = (uint32_t*)h0;   // bucket-sorted packed edges (6.4MB) alias h0

    const float* bp  = stgf + 32768;
    const float* gm  = stgf + 32896;
    const float* bt  = stgf + 33024;
    const float* qw  = stgf + 33152;
    const float* qb  = stgf + 33280;
    const float* clw = stgf + 98832;
    const float* clb = stgf + 99728;

    // host-side dtype detection from byte sizes; -1 = unknown -> guarded dual launch
    int hostflag = -1;
    if (in_sizes && n_in >= 3) {
        if      (in_sizes[2] == 32768 * 4) hostflag = 1;
        else if (in_sizes[2] == 32768 * 2) hostflag = 0;
        else if (in_sizes[0] == N_NODES * IN_DIM * 4) hostflag = 1;
        else if (in_sizes[0] == N_NODES * IN_DIM * 2) hostflag = 0;
    }
    if (hostflag >= 0) k_setflag<<<1, 64, 0, stream>>>(flag, hostflag);
    else               k_detect<<<1, 64, 0, stream>>>((const uint32_t*)d_in[2], flag);

    k_cvt<<<(99720 + 255) / 256, 256, 0, stream>>>(d_in[2], d_in[3], d_in[4], d_in[5], d_in[6],
                                                   d_in[7], d_in[8], d_in[9], d_in[10], stgf, flag);
    k_wsplit<<<(98304 + 255) / 256, 256, 0, stream>>>(stgf, wpkhi, wpklo, cwkhi, cwklo);

    k_hist<<<NCH, 256, 0, stream>>>(row, hist);
    k_hscan<<<NBK, 128, 0, stream>>>(hist, totB);
    k_bscan<<<1, 256, 0, stream>>>(totB, boffB, rp);
    k_sortscat<<<NCH, 256, 0, stream>>>(row, col, hist, boffB, ebp);
    k_bfin<<<NBK, 256, 0, stream>>>(ebp, boffB, rp, dis, edc);

    const int gg = (N_NODES + 127) / 128;   // 782
    if (hostflag != 0)
        k_gemm<IN_DIM, 0, 1, 1, 1, 0><<<gg, 256, 0, stream>>>(
            x_raw, nullptr, nullptr, wpkhi, wpklo, bp, gm, bt, qw, qb, 0.f, flag, dis,
            h0, hq, Scq, Sg, clw, clb, d_out);
    if (hostflag != 1)
        k_gemm<IN_DIM, 0, 1, 1, 0, 0><<<gg, 256, 0, stream>>>(
            x_raw, nullptr, nullptr, wpkhi, wpklo, bp, gm, bt, qw, qb, 0.f, flag, dis,
            h0, hq, Scq, Sg, clw, clb, d_out);

    for (int i = 0; i < N_LAYERS; i++) {
        k_spmm<<<(N_NODES + 3) / 4, 256, 0, stream>>>(hq, Scq, h0, rp, edc, Sg, dis, suphi, suplo);
        float theta = 0.5f / (float)(i + 1);
        const uint16_t* whi = cwkhi + (size_t)i * 16384;
        const uint16_t* wlo = cwklo + (size_t)i * 16384;
        if (i < N_LAYERS - 1) {
            if (hostflag != 0)
                k_gemm<HID, 1, 0, 1, 1, 0><<<gg, 256, 0, stream>>>(
                    nullptr, suphi, suplo, whi, wlo, nullptr, gm, bt, qw, qb, theta, flag, dis,
                    nullptr, hq, Scq, Sg, clw, clb, d_out);
            if (hostflag != 1)
                k_gemm<HID, 1, 0, 1, 0, 0><<<gg, 256, 0, stream>>>(
                    nullptr, suphi, suplo, whi, wlo, nullptr, gm, bt, qw, qb, theta, flag, dis,
                    nullptr, hq, Scq, Sg, clw, clb, d_out);
        } else {
            // last layer: classifier fused, no final h materialized
            if (hostflag != 0)
                k_gemm<HID, 1, 0, 0, 1, 1><<<gg, 256, 0, stream>>>(
                    nullptr, suphi, suplo, whi, wlo, nullptr, gm, bt, qw, qb, theta, flag, dis,
                    nullptr, hq, Scq, Sg, clw, clb, d_out);
            if (hostflag != 1)
                k_gemm<HID, 1, 0, 0, 0, 1><<<gg, 256, 0, stream>>>(
                    nullptr, suphi, suplo, whi, wlo, nullptr, gm, bt, qw, qb, theta, flag, dis,
                    nullptr, hq, Scq, Sg, clw, clb, d_out);
        }
    }
}

// Round 12
// 756.957 us; speedup vs baseline: 1.0995x; 1.0038x over previous
//
#include <hip/hip_runtime.h>
#include <hip/hip_bf16.h>
#include <hip/hip_fp16.h>
#include <stdint.h>

#define N_NODES 100000
#define N_EDGES 1600000
#define IN_DIM 256
#define HID 128
#define N_LAYERS 4
#define OUT_DIM 7
#define LN_EPS 1e-5f

// counting-sort CSR build
#define BSHIFT 6
#define BROWS 64
#define NBK 1563                  // ceil(100000/64) buckets of 64 rows
#define CHUNK 16384               // edges per sort block
#define NCH ((N_EDGES + CHUNK - 1) / CHUNK)   // 98 (must be <= 128 for k_hscan)

typedef __attribute__((ext_vector_type(8))) short bf16x8;
typedef __attribute__((ext_vector_type(4))) float f32x4;

__device__ inline float bf2f1(uint16_t u) {
    union { uint32_t i; float f; } a; a.i = ((uint32_t)u) << 16; return a.f;
}
__device__ inline uint16_t f2bf(float f) {
    union { float f; uint32_t i; } a; a.f = f;
    uint32_t lsb = (a.i >> 16) & 1u;
    a.i += 0x7fffu + lsb;          // round-to-nearest-even
    return (uint16_t)(a.i >> 16);
}
__device__ inline uint32_t packq(float a, float b, float qinv) {
    int qa = __float2int_rn(a * qinv);
    int qb = __float2int_rn(b * qinv);
    return ((uint32_t)(uint16_t)(short)qa) | (((uint32_t)(uint16_t)(short)qb) << 16);
}

// async global->LDS copy, 16B per lane (HW: wave-uniform LDS base + lane*16)
__device__ inline void g2lds16(const uint16_t* g, uint16_t* l) {
    __builtin_amdgcn_global_load_lds(
        (const __attribute__((address_space(1))) void*)g,
        (__attribute__((address_space(3))) void*)l, 16, 0, 0);
}

// fragment-order W pack: lane-linear so LDS B-frag read is one contiguous 16B.
// element (k, c) of W[KD][128] -> ((ksg*8 + ct)*64 + lane)*8 + e
__device__ __host__ inline int wpack_idx(int k, int c) {
    int ksg = k >> 5, lg = (k >> 3) & 3, e = k & 7;
    int ct = c >> 4, li = c & 15;
    return ((ksg * 8 + ct) * 64 + (lg * 16 + li)) * 8 + e;
}

// ---------------- dtype detection ----------------
__global__ void k_detect(const uint32_t* __restrict__ W, int* __restrict__ flag) {
    if (threadIdx.x == 0 && blockIdx.x == 0) {
        int cnt = 0;
        for (int i = 0; i < 64; i++) {
            uint32_t lo = W[i] & 0xffffu;
            uint32_t ex = (lo >> 7) & 0xff;
            if (ex >= 0x60 && ex < 0x7c) cnt++;
        }
        *flag = (cnt < 32) ? 1 : 0;   // 1 = fp32 inputs, 0 = bf16 inputs
    }
}
__global__ void k_setflag(int* __restrict__ flag, int v) {
    if (threadIdx.x == 0) *flag = v;
}

// ---------------- weight canonicalization (all weights -> fp32 staged) ----------------
__global__ __launch_bounds__(256) void k_cvt(const void* a0, const void* a1, const void* a2,
                                             const void* a3, const void* a4, const void* a5,
                                             const void* a6, const void* a7, const void* a8,
                                             float* __restrict__ dst, const int* __restrict__ flag) {
    int t = blockIdx.x * 256 + threadIdx.x;
    if (t >= 99720) return;
    const void* src; int i; int off;
    if      (t < 32768) { src = a0; i = t;         off = 0;     }   // W_proj 256x128
    else if (t < 32896) { src = a1; i = t - 32768; off = 32768; }   // b_proj 128
    else if (t < 33024) { src = a2; i = t - 32896; off = 32896; }   // gamma 128
    else if (t < 33152) { src = a3; i = t - 33024; off = 33024; }   // beta 128
    else if (t < 33280) { src = a4; i = t - 33152; off = 33152; }   // q_w 128
    else if (t < 33281) { src = a5; i = t - 33280; off = 33280; }   // q_b 1
    else if (t < 98817) { src = a6; i = t - 33281; off = 33296; }   // conv_w 4x128x128
    else if (t < 99713) { src = a7; i = t - 98817; off = 98832; }   // cls_w 128x7
    else                { src = a8; i = t - 99713; off = 99728; }   // cls_b 7
    float v;
    if (*flag) v = ((const float*)src)[i];
    else       v = bf2f1(((const uint16_t*)src)[i]);
    dst[off + i] = v;
}

// ---------------- split-bf16 weight prep, fragment/lane-ordered ----------------
__global__ __launch_bounds__(256) void k_wsplit(const float* __restrict__ stg,
                                                uint16_t* __restrict__ wpkhi, uint16_t* __restrict__ wpklo,
                                                uint16_t* __restrict__ cwkhi, uint16_t* __restrict__ cwklo) {
    int t = blockIdx.x * 256 + threadIdx.x;
    if (t >= 32768 + 65536) return;
    float v; size_t dst; uint16_t *ha, *la;
    if (t < 32768) {
        int k = t >> 7, c = t & 127;
        v = stg[t];
        dst = (size_t)wpack_idx(k, c); ha = wpkhi; la = wpklo;
    } else {
        int u = t - 32768;
        int L = u >> 14, rem = u & 16383;
        int k = rem >> 7, c = rem & 127;
        v = stg[33296 + u];
        dst = (size_t)L * 16384 + wpack_idx(k, c); ha = cwkhi; la = cwklo;
    }
    uint16_t hb = f2bf(v);
    uint16_t lb = f2bf(v - bf2f1(hb));
    ha[dst] = hb; la[dst] = lb;
}

// ---------------- graph prep: atomic-free counting-sort CSR build ----------------

__global__ __launch_bounds__(256) void k_hist(const int* __restrict__ row, int* __restrict__ hist) {
    __shared__ int lh[NBK];
    int b = blockIdx.x, tid = threadIdx.x;
    for (int i = tid; i < NBK; i += 256) lh[i] = 0;
    __syncthreads();
    int e0 = b * CHUNK;
    int lim = N_EDGES - e0; if (lim > CHUNK) lim = CHUNK;
    for (int i = tid; i < lim; i += 256) atomicAdd(&lh[row[e0 + i] >> BSHIFT], 1);
    __syncthreads();
    for (int i = tid; i < NBK; i += 256) hist[(size_t)b * NBK + i] = lh[i];
}

__global__ __launch_bounds__(128) void k_hscan(int* __restrict__ hist, int* __restrict__ totB) {
    __shared__ int s[128];
    int bkt = blockIdx.x, t = threadIdx.x;
    int v = (t < NCH) ? hist[(size_t)t * NBK + bkt] : 0;
    s[t] = v;
    __syncthreads();
    for (int off = 1; off < 128; off <<= 1) {
        int add = (t >= off) ? s[t - off] : 0;
        __syncthreads();
        s[t] += add;
        __syncthreads();
    }
    if (t < NCH) hist[(size_t)t * NBK + bkt] = s[t] - v;   // exclusive within bucket
    if (t == 127) totB[bkt] = s[127];
}

__global__ __launch_bounds__(256) void k_bscan(const int* __restrict__ totB,
                                               int* __restrict__ boffB, int* __restrict__ rp) {
    __shared__ int ps[256];
    int t = threadIdx.x;
    const int STRIP = 7;                     // 256*7 = 1792 >= NBK
    int base = t * STRIP;
    int loc[STRIP]; int sum = 0;
#pragma unroll
    for (int j = 0; j < STRIP; j++) {
        int idx = base + j;
        int v = (idx < NBK) ? totB[idx] : 0;
        loc[j] = sum; sum += v;
    }
    ps[t] = sum;
    __syncthreads();
    int v = ps[t];
    for (int off = 1; off < 256; off <<= 1) {
        int add = (t >= off) ? ps[t - off] : 0;
        __syncthreads();
        ps[t] += add;
        __syncthreads();
    }
    int excl = ps[t] - v;
#pragma unroll
    for (int j = 0; j < STRIP; j++) {
        int idx = base + j;
        if (idx < NBK) boffB[idx] = excl + loc[j];
    }
    if (t == 0) { boffB[NBK] = N_EDGES; rp[N_NODES] = N_EDGES; }
}

__global__ __launch_bounds__(256) void k_sortscat(const int* __restrict__ row, const int* __restrict__ col,
                                                  const int* __restrict__ hist, const int* __restrict__ boffB,
                                                  uint32_t* __restrict__ ebp) {
    __shared__ int dbase[NBK];
    __shared__ int lcnt[NBK];
    int b = blockIdx.x, tid = threadIdx.x;
    for (int i = tid; i < NBK; i += 256) {
        dbase[i] = boffB[i] + hist[(size_t)b * NBK + i];
        lcnt[i] = 0;
    }
    __syncthreads();
    int e0 = b * CHUNK;
    int lim = N_EDGES - e0; if (lim > CHUNK) lim = CHUNK;
    for (int i = tid; i < lim; i += 256) {
        int r = row[e0 + i], c = col[e0 + i];
        int bk = r >> BSHIFT;
        int rank = atomicAdd(&lcnt[bk], 1);
        ebp[dbase[bk] + rank] = ((uint32_t)(r & (BROWS - 1)) << 17) | (uint32_t)c;
    }
}

__global__ __launch_bounds__(256) void k_bfin(const uint32_t* __restrict__ ebp, const int* __restrict__ boffB,
                                              int* __restrict__ rp, float* __restrict__ dis,
                                              int* __restrict__ edc) {
    __shared__ int ldeg[BROWS];
    __shared__ int lcur[BROWS];
    int b = blockIdx.x, tid = threadIdx.x;
    int base = boffB[b];
    int n = boffB[b + 1] - base;
    if (tid < BROWS) ldeg[tid] = 0;
    __syncthreads();
    for (int i = tid; i < n; i += 256) atomicAdd(&ldeg[ebp[base + i] >> 17], 1);
    __syncthreads();
    if (tid == 0) {
        int run = 0;
        for (int r = 0; r < BROWS; r++) { int d = ldeg[r]; lcur[r] = run; run += d; }
    }
    __syncthreads();
    int row0 = b << BSHIFT;
    if (tid < BROWS && row0 + tid < N_NODES) {
        int d = ldeg[tid];
        rp[row0 + tid]  = base + lcur[tid];
        dis[row0 + tid] = rsqrtf((float)(d > 0 ? d : 1));
    }
    __syncthreads();   // rp/dis read lcur before scatter mutates it
    for (int i = tid; i < n; i += 256) {
        uint32_t pk = ebp[base + i];
        int r = pk >> 17;
        int pos = atomicAdd(&lcur[r], 1);
        edc[base + pos] = (int)(pk & 0x1FFFFu);
    }
}

// ---------------- fused SpMM + blend (int16 mirror + per-row scale) ----------------
// Proven config: unroll 8 (VGPR 32, ~70% occ, 73.5us). Unroll 16 regressed (round 9:
// VGPR 44, occ 45%, 96.7us). bf16 prescaled Hq broke numerics (round 7). Do not touch.

__global__ __launch_bounds__(256) void k_spmm(const uint32_t* __restrict__ Hq,
                                              const float* __restrict__ ScD,
                                              const float* __restrict__ H0,
                                              const int* __restrict__ rp,
                                              const int* __restrict__ edc,
                                              const float* __restrict__ S,
                                              const float* __restrict__ dis,
                                              uint16_t* __restrict__ SupHi,
                                              uint16_t* __restrict__ SupLo) {
    int wid  = (blockIdx.x * 256 + threadIdx.x) >> 6;
    int lane = threadIdx.x & 63;
    if (wid >= N_NODES) return;

    float s  = S[wid];
    float dr = dis[wid];
    float h0x = H0[(size_t)wid * 128 + lane];
    float h0y = H0[(size_t)wid * 128 + 64 + lane];

    int p0 = rp[wid], p1 = rp[wid + 1];
    float ax = 0.f, ay = 0.f;
    int p = p0;
    for (; p + 8 <= p1; p += 8) {
        int c[8]; uint32_t u[8]; float w[8];
#pragma unroll
        for (int j = 0; j < 8; j++) c[j] = edc[p + j];
#pragma unroll
        for (int j = 0; j < 8; j++) u[j] = Hq[(size_t)c[j] * 64 + lane];
#pragma unroll
        for (int j = 0; j < 8; j++) w[j] = ScD[c[j]];
#pragma unroll
        for (int j = 0; j < 8; j++) {
            ax += w[j] * (float)((int)(u[j] << 16) >> 16);
            ay += w[j] * (float)((int)u[j] >> 16);
        }
    }
    for (; p + 4 <= p1; p += 4) {
        int c[4]; uint32_t u[4]; float w[4];
#pragma unroll
        for (int j = 0; j < 4; j++) c[j] = edc[p + j];
#pragma unroll
        for (int j = 0; j < 4; j++) u[j] = Hq[(size_t)c[j] * 64 + lane];
#pragma unroll
        for (int j = 0; j < 4; j++) w[j] = ScD[c[j]];
#pragma unroll
        for (int j = 0; j < 4; j++) {
            ax += w[j] * (float)((int)(u[j] << 16) >> 16);
            ay += w[j] * (float)((int)u[j] >> 16);
        }
    }
    for (; p < p1; p++) {
        int c = edc[p];
        uint32_t u = Hq[(size_t)c * 64 + lane];
        float w = ScD[c];
        ax += w * (float)((int)(u << 16) >> 16);
        ay += w * (float)((int)u >> 16);
    }
    float f = (1.f - s) * dr;
    float ox = f * ax + s * h0x;
    float oy = f * ay + s * h0y;
    uint16_t hx = f2bf(ox), hy = f2bf(oy);
    uint16_t lx = f2bf(ox - bf2f1(hx)), ly = f2bf(oy - bf2f1(hy));
    SupHi[(size_t)wid * 128 + lane]      = hx;
    SupHi[(size_t)wid * 128 + 64 + lane] = hy;
    SupLo[(size_t)wid * 128 + lane]      = lx;
    SupLo[(size_t)wid * 128 + 64 + lane] = ly;
}

// ---------------- MFMA GEMM: W 128-K chunk in LDS, A in regs, LN/gate/quant ----------
// EXACT round-6 TU structure (750us proven; every GEMM <= 73.4us). The WC-fused
// classifier variant (rounds 7-11) regressed MODE-0 to 97-99us (co-compiled template
// instantiations perturb regalloc, rule #19) -- classifier stays a separate kernel.
// ONE change vs round 6: W staged via __builtin_amdgcn_global_load_lds width=16
// (no VGPR roundtrip, no staging VALU; packed layout == wave-linear, bit-identical).
// Block = 128 rows, 4 waves; wave wv owns rows wb=wv*32 + {li, li+16} (two acc sets).
// C layout: col=lane&15, row=(lane>>4)*4+reg (per 16-row set).
// Split products: C = Ah*Wh [+ Al*Wh if A fp32] [+ Ah*Wl if W fp32].

template <int KD, int MODE, int WH, int WQ, int WF>
__global__ __launch_bounds__(256, 2) void k_gemm(
    const void* __restrict__ Ax,
    const uint16_t* __restrict__ Ahi, const uint16_t* __restrict__ Alo,
    const uint16_t* __restrict__ Wh, const uint16_t* __restrict__ Wl,
    const float* __restrict__ bias, const float* __restrict__ gamma,
    const float* __restrict__ beta, const float* __restrict__ qw,
    const float* __restrict__ qb, float theta, const int* __restrict__ flag,
    const float* __restrict__ dis,
    float* __restrict__ Hout, uint32_t* __restrict__ Hq,
    float* __restrict__ Sc, float* __restrict__ S)
{
    if (*flag != WF) return;             // guarded dual-launch fallback
    constexpr int F32A = (MODE == 0) ? WF : 1;   // A has a lo plane
    constexpr int NKB = KD / 128;

    __shared__ __align__(16) uint16_t sWh[16384];   // 32 KiB
    __shared__ __align__(16) uint16_t sWl[16384];   // 32 KiB -> 64 KiB total

    const int tid  = threadIdx.x;
    const int lane = tid & 63;
    const int wv   = tid >> 6;
    const int li   = lane & 15;
    const int lg   = lane >> 4;
    const size_t row0 = (size_t)blockIdx.x * 128;
    const int wb = wv * 32;
    size_t ar0 = row0 + wb + li;      if (ar0 >= N_NODES) ar0 = N_NODES - 1;
    size_t ar1 = row0 + wb + 16 + li; if (ar1 >= N_NODES) ar1 = N_NODES - 1;

    f32x4 acc0[8], acc1[8];
#pragma unroll
    for (int ct = 0; ct < 8; ct++) {
        acc0[ct] = (f32x4){0.f, 0.f, 0.f, 0.f};
        acc1[ct] = (f32x4){0.f, 0.f, 0.f, 0.f};
    }

    for (int kb = 0; kb < NKB; kb++) {
        if (kb) __syncthreads();
        // ---- W chunk -> LDS via async global_load_lds (wave-uniform base + lane*16) --
        const uint16_t* gh = Wh + kb * 16384;
#pragma unroll
        for (int it = 0; it < 8; it++) {
            const int sb = (it * 256 + wv * 64) * 8;   // shorts; wave-uniform
            g2lds16(gh + sb + lane * 8, sWh + sb);
        }
        if constexpr (WF) {
            const uint16_t* gl = Wl + kb * 16384;
#pragma unroll
            for (int it = 0; it < 8; it++) {
                const int sb = (it * 256 + wv * 64) * 8;
                g2lds16(gl + sb + lane * 8, sWl + sb);
            }
        }
        // ---- A fragments -> regs (latency hidden under async staging + barrier) ----
        bf16x8 a0h[4], a1h[4], a0l[4], a1l[4];
#pragma unroll
        for (int s = 0; s < 4; s++) {
            const int koff = kb * 128 + s * 32 + lg * 8;
            if constexpr (MODE == 1) {
                a0h[s] = *(const bf16x8*)(Ahi + ar0 * KD + koff);
                a0l[s] = *(const bf16x8*)(Alo + ar0 * KD + koff);
                a1h[s] = *(const bf16x8*)(Ahi + ar1 * KD + koff);
                a1l[s] = *(const bf16x8*)(Alo + ar1 * KD + koff);
            } else if constexpr (WF) {
                const float* p0 = (const float*)Ax + ar0 * KD + koff;
                const float* p1 = (const float*)Ax + ar1 * KD + koff;
                float4 u0 = *(const float4*)p0, u1 = *(const float4*)(p0 + 4);
                float4 v0 = *(const float4*)p1, v1 = *(const float4*)(p1 + 4);
                float f0[8] = {u0.x, u0.y, u0.z, u0.w, u1.x, u1.y, u1.z, u1.w};
                float f1[8] = {v0.x, v0.y, v0.z, v0.w, v1.x, v1.y, v1.z, v1.w};
#pragma unroll
                for (int j = 0; j < 8; j++) {
                    uint16_t hb0 = f2bf(f0[j]);
                    a0h[s][j] = (short)hb0;
                    a0l[s][j] = (short)f2bf(f0[j] - bf2f1(hb0));
                    uint16_t hb1 = f2bf(f1[j]);
                    a1h[s][j] = (short)hb1;
                    a1l[s][j] = (short)f2bf(f1[j] - bf2f1(hb1));
                }
            } else {
                a0h[s] = *(const bf16x8*)((const uint16_t*)Ax + ar0 * KD + koff);
                a1h[s] = *(const bf16x8*)((const uint16_t*)Ax + ar1 * KD + koff);
            }
        }
        __syncthreads();   // drains vmcnt (incl. global_load_lds) + lgkmcnt
        // ---- barrier-free MFMA loop: all operands LDS/regs ----
#pragma unroll
        for (int s = 0; s < 4; s++) {
#pragma unroll
            for (int ct = 0; ct < 8; ct++) {
                const int wo = ((s * 8 + ct) * 64 + lane) * 8;
                bf16x8 bh = *(const bf16x8*)(sWh + wo);
                acc0[ct] = __builtin_amdgcn_mfma_f32_16x16x32_bf16(a0h[s], bh, acc0[ct], 0, 0, 0);
                acc1[ct] = __builtin_amdgcn_mfma_f32_16x16x32_bf16(a1h[s], bh, acc1[ct], 0, 0, 0);
                if constexpr (F32A) {
                    acc0[ct] = __builtin_amdgcn_mfma_f32_16x16x32_bf16(a0l[s], bh, acc0[ct], 0, 0, 0);
                    acc1[ct] = __builtin_amdgcn_mfma_f32_16x16x32_bf16(a1l[s], bh, acc1[ct], 0, 0, 0);
                }
                if constexpr (WF) {
                    bf16x8 bl = *(const bf16x8*)(sWl + wo);
                    acc0[ct] = __builtin_amdgcn_mfma_f32_16x16x32_bf16(a0h[s], bl, acc0[ct], 0, 0, 0);
                    acc1[ct] = __builtin_amdgcn_mfma_f32_16x16x32_bf16(a1h[s], bl, acc1[ct], 0, 0, 0);
                }
            }
        }
    }

    // ---- epilogue: per (lane, reg, set) one row, cols {ct*16+li} ----
    float gm[8], bt_[8], qv[8], bi[8];
#pragma unroll
    for (int ct = 0; ct < 8; ct++) {
        int c = ct * 16 + li;
        gm[ct] = gamma[c]; bt_[ct] = beta[c]; qv[ct] = qw[c];
        bi[ct] = (MODE == 0) ? bias[c] : 0.f;
    }
    const float qbv = qb[0];
    const float om  = 1.f - theta;

    auto epi = [&](f32x4 (&acc)[8], int ssoff) {
#pragma unroll
        for (int r = 0; r < 4; r++) {
            int rowl  = wb + ssoff + lg * 4 + r;
            size_t rg = row0 + rowl;
            size_t rc = (rg < N_NODES) ? rg : (N_NODES - 1);
            float v[8];
            if (MODE == 0) {
#pragma unroll
                for (int ct = 0; ct < 8; ct++) v[ct] = acc[ct][r] + bi[ct];
            } else {
#pragma unroll
                for (int ct = 0; ct < 8; ct++) {
                    int c = ct * 16 + li;
                    float sv = bf2f1(Ahi[rc * KD + c]) + bf2f1(Alo[rc * KD + c]);
                    float o  = theta * acc[ct][r] + om * sv;
                    v[ct] = o > 0.f ? o : 0.f;
                }
            }
            float sum = 0.f, sq = 0.f;
#pragma unroll
            for (int ct = 0; ct < 8; ct++) { sum += v[ct]; sq += v[ct] * v[ct]; }
            sum += __shfl_xor(sum, 1); sum += __shfl_xor(sum, 2);
            sum += __shfl_xor(sum, 4); sum += __shfl_xor(sum, 8);
            sq  += __shfl_xor(sq, 1);  sq  += __shfl_xor(sq, 2);
            sq  += __shfl_xor(sq, 4);  sq  += __shfl_xor(sq, 8);
            float mu  = sum * (1.f / 128.f);
            float var = fmaxf(sq * (1.f / 128.f) - mu * mu, 0.f);
            float rs  = rsqrtf(var + LN_EPS);
            float y[8];
#pragma unroll
            for (int ct = 0; ct < 8; ct++) y[ct] = gm[ct] * (v[ct] - mu) * rs + bt_[ct];

            if (WQ) {
                float zd = 0.f, am = 0.f;
#pragma unroll
                for (int ct = 0; ct < 8; ct++) { zd += y[ct] * qv[ct]; am = fmaxf(am, fabsf(y[ct])); }
                zd += __shfl_xor(zd, 1); zd += __shfl_xor(zd, 2);
                zd += __shfl_xor(zd, 4); zd += __shfl_xor(zd, 8);
                am = fmaxf(am, __shfl_xor(am, 1)); am = fmaxf(am, __shfl_xor(am, 2));
                am = fmaxf(am, __shfl_xor(am, 4)); am = fmaxf(am, __shfl_xor(am, 8));
                float amc  = fmaxf(am, 1e-20f);
                float qinv = 32767.f / amc;
                if (rg < N_NODES) {
                    uint32_t* mq = Hq + rg * 64;
#pragma unroll
                    for (int ct = 0; ct < 4; ct++)
                        mq[ct * 16 + li] = packq(y[ct], y[ct + 4], qinv);  // pair (c, c+64)
                    if (li == 0) {
                        Sc[rg] = amc * (1.f / 32767.f) * dis[rg];   // fold dis[col] into scale
                        S[rg]  = 1.f / (1.f + __expf(-(zd + qbv - 1.f)));
                    }
                }
            }
            if (WH && rg < N_NODES) {
                float* dst = Hout + rg * 128;
#pragma unroll
                for (int ct = 0; ct < 8; ct++) dst[ct * 16 + li] = y[ct];
            }
        }
    };
    epi(acc0, 0);
    epi(acc1, 16);
}

// ---------------- classifier (fp32 in, dtype-flag out) ----------------

__global__ __launch_bounds__(256) void k_cls(const float* __restrict__ H,
                                             const float* __restrict__ Wc,
                                             const float* __restrict__ bc,
                                             const int* __restrict__ flag,
                                             void* __restrict__ out) {
    __shared__ float wS[128][8];
    int tid = threadIdx.x;
    for (int idx = tid; idx < 128 * 7; idx += 256) wS[idx / 7][idx % 7] = Wc[idx];
    __syncthreads();
    int isf32 = *flag;
    int gid = blockIdx.x * 256 + tid;
    int n = gid >> 3, j = gid & 7;
    if (n >= N_NODES || j >= OUT_DIM) return;
    const float4* hr = (const float4*)(H + (size_t)n * 128);
    float acc = bc[j];
#pragma unroll
    for (int k4 = 0; k4 < 32; k4++) {
        float4 h4 = hr[k4];
        acc += h4.x * wS[4 * k4][j]     + h4.y * wS[4 * k4 + 1][j]
             + h4.z * wS[4 * k4 + 2][j] + h4.w * wS[4 * k4 + 3][j];
    }
    size_t oi = (size_t)n * OUT_DIM + j;
    if (isf32) ((float*)out)[oi] = acc;
    else       ((uint16_t*)out)[oi] = f2bf(acc);
}

// ---------------- launch ----------------

extern "C" void kernel_launch(void* const* d_in, const int* in_sizes, int n_in,
                              void* d_out, int out_size, void* d_ws, size_t ws_size,
                              hipStream_t stream) {
    const void* x_raw = d_in[0];
    const int*  ei    = (const int*)d_in[1];
    const int* row = ei;
    const int* col = ei + N_EDGES;

    char* ws = (char*)d_ws;
    size_t off = 0;
    auto alloc = [&](size_t b) { void* p = ws + off; off = (off + b + 255) & ~(size_t)255; return p; };
    int*      flag = (int*)alloc(4);
    float*    stgf = (float*)alloc((size_t)99744 * 4);
    int*      rp   = (int*)alloc(((size_t)N_NODES + 1) * 4);
    float*    dis  = (float*)alloc((size_t)N_NODES * 4);
    int*      hist = (int*)alloc((size_t)NCH * NBK * 4);
    int*      totB = (int*)alloc((size_t)NBK * 4);
    int*      boffB= (int*)alloc(((size_t)NBK + 1) * 4);
    int*      edc  = (int*)alloc((size_t)N_EDGES * 4);             // CSR cols (4B)
    float*    h0   = (float*)alloc((size_t)N_NODES * HID * 4);     // h0; last GEMM writes h here
    uint16_t* suphi= (uint16_t*)alloc((size_t)N_NODES * HID * 2);  // support hi plane
    uint16_t* suplo= (uint16_t*)alloc((size_t)N_NODES * HID * 2);  // support lo plane
    uint32_t* hq   = (uint32_t*)alloc((size_t)N_NODES * 64 * 4);   // int16 mirror
    float*    Scq  = (float*)alloc((size_t)N_NODES * 4);           // quant scale * dis
    float*    Sg   = (float*)alloc((size_t)N_NODES * 4);           // gate sigmoid
    uint16_t* wpkhi = (uint16_t*)alloc((size_t)32768 * 2);         // W_proj packed hi
    uint16_t* wpklo = (uint16_t*)alloc((size_t)32768 * 2);
    uint16_t* cwkhi = (uint16_t*)alloc((size_t)65536 * 2);         // conv_w packed hi (4 layers)
    uint16_t* cwklo = (uint16_t*)alloc((size_t)65536 * 2);
    uint32_t* ebp  = (uint32_t*)h0;   // bucket-sorted packed edges (6.4MB) alias h0

    const float* bp  = stgf + 32768;
    const float* gm  = stgf + 32896;
    const float* bt  = stgf + 33024;
    const float* qw  = stgf + 33152;
    const float* qb  = stgf + 33280;
    const float* clw = stgf + 98832;
    const float* clb = stgf + 99728;

    // host-side dtype detection from byte sizes; -1 = unknown -> guarded dual launch
    int hostflag = -1;
    if (in_sizes && n_in >= 3) {
        if      (in_sizes[2] == 32768 * 4) hostflag = 1;
        else if (in_sizes[2] == 32768 * 2) hostflag = 0;
        else if (in_sizes[0] == N_NODES * IN_DIM * 4) hostflag = 1;
        else if (in_sizes[0] == N_NODES * IN_DIM * 2) hostflag = 0;
    }
    if (hostflag >= 0) k_setflag<<<1, 64, 0, stream>>>(flag, hostflag);
    else               k_detect<<<1, 64, 0, stream>>>((const uint32_t*)d_in[2], flag);

    k_cvt<<<(99720 + 255) / 256, 256, 0, stream>>>(d_in[2], d_in[3], d_in[4], d_in[5], d_in[6],
                                                   d_in[7], d_in[8], d_in[9], d_in[10], stgf, flag);
    k_wsplit<<<(98304 + 255) / 256, 256, 0, stream>>>(stgf, wpkhi, wpklo, cwkhi, cwklo);

    k_hist<<<NCH, 256, 0, stream>>>(row, hist);
    k_hscan<<<NBK, 128, 0, stream>>>(hist, totB);
    k_bscan<<<1, 256, 0, stream>>>(totB, boffB, rp);
    k_sortscat<<<NCH, 256, 0, stream>>>(row, col, hist, boffB, ebp);
    k_bfin<<<NBK, 256, 0, stream>>>(ebp, boffB, rp, dis, edc);

    const int gg = (N_NODES + 127) / 128;   // 782
    if (hostflag != 0)
        k_gemm<IN_DIM, 0, 1, 1, 1><<<gg, 256, 0, stream>>>(
            x_raw, nullptr, nullptr, wpkhi, wpklo, bp, gm, bt, qw, qb, 0.f, flag, dis,
            h0, hq, Scq, Sg);
    if (hostflag != 1)
        k_gemm<IN_DIM, 0, 1, 1, 0><<<gg, 256, 0, stream>>>(
            x_raw, nullptr, nullptr, wpkhi, wpklo, bp, gm, bt, qw, qb, 0.f, flag, dis,
            h0, hq, Scq, Sg);

    for (int i = 0; i < N_LAYERS; i++) {
        k_spmm<<<(N_NODES + 3) / 4, 256, 0, stream>>>(hq, Scq, h0, rp, edc, Sg, dis, suphi, suplo);
        float theta = 0.5f / (float)(i + 1);
        const uint16_t* whi = cwkhi + (size_t)i * 16384;
        const uint16_t* wlo = cwklo + (size_t)i * 16384;
        if (i < N_LAYERS - 1) {
            if (hostflag != 0)
                k_gemm<HID, 1, 0, 1, 1><<<gg, 256, 0, stream>>>(
                    nullptr, suphi, suplo, whi, wlo, nullptr, gm, bt, qw, qb, theta, flag, dis,
                    nullptr, hq, Scq, Sg);
            if (hostflag != 1)
                k_gemm<HID, 1, 0, 1, 0><<<gg, 256, 0, stream>>>(
                    nullptr, suphi, suplo, whi, wlo, nullptr, gm, bt, qw, qb, theta, flag, dis,
                    nullptr, hq, Scq, Sg);
        } else {
            // last layer: write h into h0 (spmm done with it); k_cls consumes it
            if (hostflag != 0)
                k_gemm<HID, 1, 1, 0, 1><<<gg, 256, 0, stream>>>(
                    nullptr, suphi, suplo, whi, wlo, nullptr, gm, bt, qw, qb, theta, flag, dis,
                    h0, hq, Scq, Sg);
            if (hostflag != 1)
                k_gemm<HID, 1, 1, 0, 0><<<gg, 256, 0, stream>>>(
                    nullptr, suphi, suplo, whi, wlo, nullptr, gm, bt, qw, qb, theta, flag, dis,
                    h0, hq, Scq, Sg);
        }
    }
    k_cls<<<((size_t)N_NODES * 8 + 255) / 256, 256, 0, stream>>>(h0, clw, clb, flag, d_out);
}